// Round 3
// baseline (1168.781 us; speedup 1.0000x reference)
//
#include <hip/hip_runtime.h>
#include <stdint.h>

#define BB   2
#define SS   2048
#define DD   1024
#define NH   16
#define RK   204
#define RKP  256
#define HDIM 64
#define BH   (BB*NH)

typedef __attribute__((ext_vector_type(8))) short short8;
typedef __attribute__((ext_vector_type(4))) float f32x4;
typedef unsigned short u16;
typedef unsigned int   u32;

#define NEGBIG (-1e30f)

static __device__ __forceinline__ u16 f2bf(float f) {
    union { float f; u32 u; } v; v.f = f;
    u32 u = v.u;
    return (u16)((u + 0x7fffu + ((u >> 16) & 1u)) >> 16);  // RNE
}
static __device__ __forceinline__ u32 pack2(float lo, float hi) {
    return (u32)f2bf(lo) | ((u32)f2bf(hi) << 16);
}

// ---------------- conversion kernels ----------------
__global__ void cvt_bf16_k(const float* __restrict__ in, u16* __restrict__ out, int n4) {
    int i = blockIdx.x * blockDim.x + threadIdx.x;
    if (i < n4) {
        float4 f = ((const float4*)in)[i];
        u32 lo = pack2(f.x, f.y), hi = pack2(f.z, f.w);
        ((uint2*)out)[i] = make_uint2(lo, hi);
    }
}

// U (DD x RK) fp32 -> (DD x RKP) bf16, zero pad cols [RK,RKP)
__global__ void cvt_pad_u_k(const float* __restrict__ in, u16* __restrict__ out) {
    int i = blockIdx.x * blockDim.x + threadIdx.x;
    if (i >= DD * RKP) return;
    int row = i >> 8, col = i & (RKP - 1);
    out[i] = (col < RK) ? f2bf(in[row * RK + col]) : (u16)0;
}

// ---------------- NT GEMM: C[M x N] = A[M x K] * B[N x K]^T (+bias) ----------------
// OUT_VT: instead of C row-major, write vT[bh][hd][s] (V-head transpose) via LDS.
template<int A_F32, int OUT_F32, int HAS_BIAS, int OUT_VT>
__global__ __launch_bounds__(256)
void gemm_nt_k(const void* __restrict__ Ap, int lda,
               const u16* __restrict__ Bp, int ldb, int nrowsB,
               const float* __restrict__ bias,
               void* __restrict__ Cp, int ldc, int K)
{
    __shared__ __align__(16) u16 As[64*72];
    __shared__ __align__(16) u16 Bs[64*72];
    const int row0 = blockIdx.x * 64;
    const int col0 = blockIdx.y * 64;
    const int t = threadIdx.x;
    const int w = t >> 6, lane = t & 63, quad = lane >> 4, l16 = lane & 15;
    const int r = t >> 2, seg = t & 3;

    f32x4 acc0 = 0.f, acc1 = 0.f, acc2 = 0.f, acc3 = 0.f;

    for (int k0 = 0; k0 < K; k0 += 64) {
        __syncthreads();
        if (A_F32) {
            const float* ga = (const float*)Ap + (size_t)(row0 + r) * lda + k0 + seg*16;
            float4 f0 = ((const float4*)ga)[0];
            float4 f1 = ((const float4*)ga)[1];
            float4 f2 = ((const float4*)ga)[2];
            float4 f3 = ((const float4*)ga)[3];
            uint4 s0 = { pack2(f0.x,f0.y), pack2(f0.z,f0.w), pack2(f1.x,f1.y), pack2(f1.z,f1.w) };
            uint4 s1 = { pack2(f2.x,f2.y), pack2(f2.z,f2.w), pack2(f3.x,f3.y), pack2(f3.z,f3.w) };
            *(uint4*)(As + r*72 + seg*16)     = s0;
            *(uint4*)(As + r*72 + seg*16 + 8) = s1;
        } else {
            const u16* ga = (const u16*)Ap + (size_t)(row0 + r) * lda + k0 + seg*16;
            *(uint4*)(As + r*72 + seg*16)     = ((const uint4*)ga)[0];
            *(uint4*)(As + r*72 + seg*16 + 8) = ((const uint4*)ga)[1];
        }
        {
            uint4 b0 = {0,0,0,0}, b1 = {0,0,0,0};
            if (col0 + r < nrowsB) {
                const u16* gb = Bp + (size_t)(col0 + r) * ldb + k0 + seg*16;
                b0 = ((const uint4*)gb)[0];
                b1 = ((const uint4*)gb)[1];
            }
            *(uint4*)(Bs + r*72 + seg*16)     = b0;
            *(uint4*)(Bs + r*72 + seg*16 + 8) = b1;
        }
        __syncthreads();
        #pragma unroll
        for (int c = 0; c < 2; ++c) {
            short8 a = *(const short8*)(As + (w*16 + l16)*72 + c*32 + quad*8);
            short8 b0v = *(const short8*)(Bs + (0*16 + l16)*72 + c*32 + quad*8);
            acc0 = __builtin_amdgcn_mfma_f32_16x16x32_bf16(a, b0v, acc0, 0, 0, 0);
            short8 b1v = *(const short8*)(Bs + (1*16 + l16)*72 + c*32 + quad*8);
            acc1 = __builtin_amdgcn_mfma_f32_16x16x32_bf16(a, b1v, acc1, 0, 0, 0);
            short8 b2v = *(const short8*)(Bs + (2*16 + l16)*72 + c*32 + quad*8);
            acc2 = __builtin_amdgcn_mfma_f32_16x16x32_bf16(a, b2v, acc2, 0, 0, 0);
            short8 b3v = *(const short8*)(Bs + (3*16 + l16)*72 + c*32 + quad*8);
            acc3 = __builtin_amdgcn_mfma_f32_16x16x32_bf16(a, b3v, acc3, 0, 0, 0);
        }
    }

    if (OUT_VT) {
        // write V-head transpose directly: vT[(bh*HDIM + hd)*SS + s]
        // col0 is 64-aligned and HDIM==64 -> this tile is exactly one head's 64 dims.
        __syncthreads();   // all waves done reading As/Bs
        #pragma unroll
        for (int f = 0; f < 4; ++f) {
            f32x4 a = (f==0) ? acc0 : (f==1) ? acc1 : (f==2) ? acc2 : acc3;
            int col = f*16 + l16;           // hd within head
            float bv = HAS_BIAS ? bias[col0 + col] : 0.f;
            #pragma unroll
            for (int rg = 0; rg < 4; ++rg) {
                int rowl = w*16 + quad*4 + rg;   // s within tile
                As[col*72 + rowl] = f2bf(a[rg] + bv);   // As reused as [hd][s]
            }
        }
        __syncthreads();
        const int b_ = row0 >> 11;          // which batch (SS=2048 rows per batch)
        const int s0 = row0 & (SS - 1);
        const int h  = col0 >> 6;
        u16* dst = (u16*)Cp + ((size_t)((b_*NH + h)*HDIM + r))*SS + s0 + seg*16;
        ((uint4*)dst)[0] = *(const uint4*)(As + r*72 + seg*16);
        ((uint4*)dst)[1] = *(const uint4*)(As + r*72 + seg*16 + 8);
        return;
    }

    #pragma unroll
    for (int f = 0; f < 4; ++f) {
        f32x4 a = (f==0) ? acc0 : (f==1) ? acc1 : (f==2) ? acc2 : acc3;
        int col = col0 + f*16 + l16;
        float bv = HAS_BIAS ? bias[col] : 0.f;
        #pragma unroll
        for (int rg = 0; rg < 4; ++rg) {
            int rowg = row0 + w*16 + quad*4 + rg;
            float val = a[rg] + bv;
            if (col >= nrowsB) val = 0.f;
            if (OUT_F32) ((float*)Cp)[(size_t)rowg*ldc + col] = val;
            else         ((u16*)Cp)[(size_t)rowg*ldc + col]  = f2bf(val);
        }
    }
}

// ---------------- fused attention: phase1 m,l + phase2 attn write + O = P*V ----------------
#define QKT_8(sa0,sa1,sa2,sa3) do { \
    short8 b0 = *(const short8*)(Ks + (0*16 + l16)*72 + quad*8); \
    sa0 = __builtin_amdgcn_mfma_f32_16x16x32_bf16(q0, b0, sa0, 0,0,0); \
    short8 b0b = *(const short8*)(Ks + (0*16 + l16)*72 + 32 + quad*8); \
    sa0 = __builtin_amdgcn_mfma_f32_16x16x32_bf16(q1, b0b, sa0, 0,0,0); \
    short8 b1 = *(const short8*)(Ks + (1*16 + l16)*72 + quad*8); \
    sa1 = __builtin_amdgcn_mfma_f32_16x16x32_bf16(q0, b1, sa1, 0,0,0); \
    short8 b1b = *(const short8*)(Ks + (1*16 + l16)*72 + 32 + quad*8); \
    sa1 = __builtin_amdgcn_mfma_f32_16x16x32_bf16(q1, b1b, sa1, 0,0,0); \
    short8 b2 = *(const short8*)(Ks + (2*16 + l16)*72 + quad*8); \
    sa2 = __builtin_amdgcn_mfma_f32_16x16x32_bf16(q0, b2, sa2, 0,0,0); \
    short8 b2b = *(const short8*)(Ks + (2*16 + l16)*72 + 32 + quad*8); \
    sa2 = __builtin_amdgcn_mfma_f32_16x16x32_bf16(q1, b2b, sa2, 0,0,0); \
    short8 b3 = *(const short8*)(Ks + (3*16 + l16)*72 + quad*8); \
    sa3 = __builtin_amdgcn_mfma_f32_16x16x32_bf16(q0, b3, sa3, 0,0,0); \
    short8 b3b = *(const short8*)(Ks + (3*16 + l16)*72 + 32 + quad*8); \
    sa3 = __builtin_amdgcn_mfma_f32_16x16x32_bf16(q1, b3b, sa3, 0,0,0); \
} while (0)

__global__ __launch_bounds__(256)
void attn_k(const u16* __restrict__ qh, const u16* __restrict__ kh,
            const u16* __restrict__ vT,
            float* __restrict__ attn_out, u16* __restrict__ Ob)
{
    __shared__ __align__(16) u16 Ks[64*72];
    __shared__ __align__(16) u16 Vs[64*72];
    __shared__ __align__(16) u16 Ps[64*72];
    const int blk = blockIdx.x;          // bh*32 + qt
    const int qt = blk & 31, bh = blk >> 5;
    const int b_ = bh >> 4, h = bh & (NH - 1);
    const int qbase = qt * 64;
    const int t = threadIdx.x, w = t >> 6, lane = t & 63, quad = lane >> 4, l16 = lane & 15;
    const int r = t >> 2, seg = t & 3;
    const float scl = 0.125f;

    const u16* qrow = qh + (size_t)(b_*SS + qbase + w*16 + l16)*DD + h*HDIM;
    short8 q0 = *(const short8*)(qrow + quad*8);
    short8 q1 = *(const short8*)(qrow + 32 + quad*8);

    const u16* kstage = kh + (size_t)(b_*SS + r)*DD + h*HDIM + seg*16;
    const u16* vstage = vT + ((size_t)(bh*HDIM + r))*SS + seg*16;

    // ---------------- phase 1: per-lane online (m,l), merge once ----------------
    float m[4], l[4];
    #pragma unroll
    for (int rg = 0; rg < 4; ++rg) { m[rg] = NEGBIG; l[rg] = 0.f; }

    for (int kt = 0; kt <= qt; ++kt) {
        __syncthreads();
        {
            const u16* krow = kstage + (size_t)kt*64*DD;
            *(uint4*)(Ks + r*72 + seg*16)     = ((const uint4*)krow)[0];
            *(uint4*)(Ks + r*72 + seg*16 + 8) = ((const uint4*)krow)[1];
        }
        __syncthreads();

        f32x4 sa0 = 0.f, sa1 = 0.f, sa2 = 0.f, sa3 = 0.f;
        QKT_8(sa0, sa1, sa2, sa3);

        if (kt < qt) {
            #pragma unroll
            for (int rg = 0; rg < 4; ++rg) {
                float v0 = sa0[rg]*scl, v1 = sa1[rg]*scl, v2 = sa2[rg]*scl, v3 = sa3[rg]*scl;
                float m4 = fmaxf(fmaxf(v0, v1), fmaxf(v2, v3));
                float nm = fmaxf(m[rg], m4);
                l[rg] = l[rg]*__expf(m[rg]-nm)
                      + (__expf(v0-nm)+__expf(v1-nm)) + (__expf(v2-nm)+__expf(v3-nm));
                m[rg] = nm;
            }
        } else {
            int key0 = kt*64 + l16;
            #pragma unroll
            for (int rg = 0; rg < 4; ++rg) {
                int qg = qbase + w*16 + quad*4 + rg;
                bool c0 = (key0      <= qg), c1 = (key0 + 16 <= qg);
                bool c2 = (key0 + 32 <= qg), c3 = (key0 + 48 <= qg);
                float v0 = c0 ? sa0[rg]*scl : NEGBIG;
                float v1 = c1 ? sa1[rg]*scl : NEGBIG;
                float v2 = c2 ? sa2[rg]*scl : NEGBIG;
                float v3 = c3 ? sa3[rg]*scl : NEGBIG;
                float m4 = fmaxf(fmaxf(v0, v1), fmaxf(v2, v3));
                float nm = fmaxf(m[rg], m4);
                float e0 = c0 ? __expf(v0-nm) : 0.f;
                float e1 = c1 ? __expf(v1-nm) : 0.f;
                float e2 = c2 ? __expf(v2-nm) : 0.f;
                float e3 = c3 ? __expf(v3-nm) : 0.f;
                float corr = (m[rg] > NEGBIG) ? __expf(m[rg]-nm) : 0.f;
                l[rg] = l[rg]*corr + (e0+e1) + (e2+e3);
                m[rg] = nm;
            }
        }
    }

    // 16-lane merge; afterwards every lane holds its rows' final (m,l)
    #pragma unroll
    for (int rg = 0; rg < 4; ++rg) {
        #pragma unroll
        for (int d = 1; d < 16; d <<= 1) {
            float mo = __shfl_xor(m[rg], d);
            float lo = __shfl_xor(l[rg], d);
            float nm = fmaxf(m[rg], mo);
            l[rg] = l[rg]*__expf(m[rg]-nm) + lo*__expf(mo-nm);
            m[rg] = nm;
        }
    }
    float mr[4], rl[4];
    #pragma unroll
    for (int rg = 0; rg < 4; ++rg) { mr[rg] = m[rg]; rl[rg] = 1.f / l[rg]; }

    // ---------------- phase 2: P write + O = P*V ----------------
    f32x4 oa0 = 0.f, oa1 = 0.f, oa2 = 0.f, oa3 = 0.f;
    float* attn_base = attn_out + (size_t)bh * SS * SS;
    float* rp0 = attn_base + (size_t)(qbase + w*16 + quad*4 + 0)*SS + l16;
    float* rp1 = attn_base + (size_t)(qbase + w*16 + quad*4 + 1)*SS + l16;
    float* rp2 = attn_base + (size_t)(qbase + w*16 + quad*4 + 2)*SS + l16;
    float* rp3 = attn_base + (size_t)(qbase + w*16 + quad*4 + 3)*SS + l16;

    for (int kt = 0; kt <= qt; ++kt) {
        __syncthreads();
        {
            const u16* krow = kstage + (size_t)kt*64*DD;
            *(uint4*)(Ks + r*72 + seg*16)     = ((const uint4*)krow)[0];
            *(uint4*)(Ks + r*72 + seg*16 + 8) = ((const uint4*)krow)[1];
            const u16* vrow = vstage + kt*64;
            *(uint4*)(Vs + r*72 + seg*16)     = ((const uint4*)vrow)[0];
            *(uint4*)(Vs + r*72 + seg*16 + 8) = ((const uint4*)vrow)[1];
        }
        __syncthreads();

        f32x4 sa0 = 0.f, sa1 = 0.f, sa2 = 0.f, sa3 = 0.f;
        QKT_8(sa0, sa1, sa2, sa3);

        if (kt < qt) {
            #pragma unroll
            for (int f = 0; f < 4; ++f) {
                f32x4 sv = (f==0) ? sa0 : (f==1) ? sa1 : (f==2) ? sa2 : sa3;
                float p0 = __expf(sv[0]*scl - mr[0]) * rl[0];
                float p1 = __expf(sv[1]*scl - mr[1]) * rl[1];
                float p2 = __expf(sv[2]*scl - mr[2]) * rl[2];
                float p3 = __expf(sv[3]*scl - mr[3]) * rl[3];
                __builtin_nontemporal_store(p0, rp0 + f*16);
                __builtin_nontemporal_store(p1, rp1 + f*16);
                __builtin_nontemporal_store(p2, rp2 + f*16);
                __builtin_nontemporal_store(p3, rp3 + f*16);
                Ps[(w*16 + quad*4 + 0)*72 + f*16 + l16] = f2bf(p0);
                Ps[(w*16 + quad*4 + 1)*72 + f*16 + l16] = f2bf(p1);
                Ps[(w*16 + quad*4 + 2)*72 + f*16 + l16] = f2bf(p2);
                Ps[(w*16 + quad*4 + 3)*72 + f*16 + l16] = f2bf(p3);
            }
        } else {
            int kbase = kt*64;
            #pragma unroll
            for (int f = 0; f < 4; ++f) {
                f32x4 sv = (f==0) ? sa0 : (f==1) ? sa1 : (f==2) ? sa2 : sa3;
                int key = kbase + f*16 + l16;
                #pragma unroll
                for (int rg = 0; rg < 4; ++rg) {
                    int qg = qbase + w*16 + quad*4 + rg;
                    float p = (key <= qg) ? __expf(sv[rg]*scl - mr[rg]) * rl[rg] : 0.f;
                    float* rp = (rg==0) ? rp0 : (rg==1) ? rp1 : (rg==2) ? rp2 : rp3;
                    __builtin_nontemporal_store(p, rp + f*16);
                    Ps[(w*16 + quad*4 + rg)*72 + f*16 + l16] = f2bf(p);
                }
            }
        }
        rp0 += 64; rp1 += 64; rp2 += 64; rp3 += 64;

        // Ps rows are wave-private (wave w writes and reads rows w*16..w*16+15);
        // per-wave LDS pipe is in-order — compiler-level fence only, no barrier.
        asm volatile("" ::: "memory");

        // O += P * V
        #pragma unroll
        for (int c = 0; c < 2; ++c) {
            short8 pa = *(const short8*)(Ps + (w*16 + l16)*72 + c*32 + quad*8);
            short8 v0 = *(const short8*)(Vs + (0*16 + l16)*72 + c*32 + quad*8);
            oa0 = __builtin_amdgcn_mfma_f32_16x16x32_bf16(pa, v0, oa0, 0,0,0);
            short8 v1 = *(const short8*)(Vs + (1*16 + l16)*72 + c*32 + quad*8);
            oa1 = __builtin_amdgcn_mfma_f32_16x16x32_bf16(pa, v1, oa1, 0,0,0);
            short8 v2 = *(const short8*)(Vs + (2*16 + l16)*72 + c*32 + quad*8);
            oa2 = __builtin_amdgcn_mfma_f32_16x16x32_bf16(pa, v2, oa2, 0,0,0);
            short8 v3 = *(const short8*)(Vs + (3*16 + l16)*72 + c*32 + quad*8);
            oa3 = __builtin_amdgcn_mfma_f32_16x16x32_bf16(pa, v3, oa3, 0,0,0);
        }
    }

    // fully-masked upper tiles: explicit zeros (d_out is poisoned)
    for (int kt = qt + 1; kt < 32; ++kt) {
        int kbase = kt * 64;
        f32x4 z = 0.f;
        float* p = attn_base + (size_t)(qbase + r)*SS + kbase + seg*16;
        __builtin_nontemporal_store(z, (f32x4*)p + 0);
        __builtin_nontemporal_store(z, (f32x4*)p + 1);
        __builtin_nontemporal_store(z, (f32x4*)p + 2);
        __builtin_nontemporal_store(z, (f32x4*)p + 3);
    }

    #pragma unroll
    for (int f = 0; f < 4; ++f) {
        f32x4 ov = (f==0) ? oa0 : (f==1) ? oa1 : (f==2) ? oa2 : oa3;
        #pragma unroll
        for (int rg = 0; rg < 4; ++rg) {
            int qg = qbase + w*16 + quad*4 + rg;
            Ob[(size_t)(b_*SS + qg)*DD + h*HDIM + f*16 + l16] = f2bf(ov[rg]);
        }
    }
}

// ---------------- launch ----------------
extern "C" void kernel_launch(void* const* d_in, const int* in_sizes, int n_in,
                              void* d_out, int out_size, void* d_ws, size_t ws_size,
                              hipStream_t stream)
{
    const float* xs[3] = { (const float*)d_in[0], (const float*)d_in[1], (const float*)d_in[2] };
    const float* Vw[4] = { (const float*)d_in[3], (const float*)d_in[6], (const float*)d_in[9],  (const float*)d_in[12] };
    const float* Uw[4] = { (const float*)d_in[4], (const float*)d_in[7], (const float*)d_in[10], (const float*)d_in[13] };
    const float* bw[4] = { (const float*)d_in[5], (const float*)d_in[8], (const float*)d_in[11], (const float*)d_in[14] };

    char* ws = (char*)d_ws;
    size_t off = 0;
    auto alloc = [&](size_t bytes) -> char* {
        char* p = ws + off;
        off += (bytes + 255) & ~(size_t)255;
        return p;
    };
    u16* wV[4]; for (int i = 0; i < 4; ++i) wV[i] = (u16*)alloc((size_t)RK*DD*2);
    u16* wU[4]; for (int i = 0; i < 4; ++i) wU[i] = (u16*)alloc((size_t)DD*RKP*2);
    u16* Tb  = (u16*)alloc((size_t)BB*SS*RKP*2);
    u16* hb[2]; for (int i = 0; i < 2; ++i) hb[i] = (u16*)alloc((size_t)BB*SS*DD*2);
    u16* vTb = (u16*)alloc((size_t)BB*SS*DD*2);
    u16* Ob  = (u16*)alloc((size_t)BB*SS*DD*2);
    (void)ws_size; (void)in_sizes; (void)n_in; (void)out_size;

    // weight conversions
    for (int i = 0; i < 4; ++i)
        cvt_bf16_k<<<(RK*DD/4 + 255)/256, 256, 0, stream>>>(Vw[i], wV[i], RK*DD/4);
    for (int i = 0; i < 4; ++i)
        cvt_pad_u_k<<<(DD*RKP + 255)/256, 256, 0, stream>>>(Uw[i], wU[i]);

    const int MROWS = BB*SS;           // 4096
    // q,k projections: X @ V^T -> T[4096x256 padded]; T @ U^T + b -> heads bf16
    for (int p = 0; p < 2; ++p) {
        gemm_nt_k<1,0,0,0><<<dim3(MROWS/64, RKP/64), 256, 0, stream>>>(
            xs[p], DD, wV[p], DD, RK, nullptr, Tb, RKP, DD);
        gemm_nt_k<0,0,1,0><<<dim3(MROWS/64, DD/64), 256, 0, stream>>>(
            Tb, RKP, wU[p], RKP, DD, bw[p], hb[p], DD, RKP);
    }
    // v projection: second GEMM writes vT[bh][hd][s] directly (transposed epilogue)
    gemm_nt_k<1,0,0,0><<<dim3(MROWS/64, RKP/64), 256, 0, stream>>>(
        xs[2], DD, wV[2], DD, RK, nullptr, Tb, RKP, DD);
    gemm_nt_k<0,0,1,1><<<dim3(MROWS/64, DD/64), 256, 0, stream>>>(
        Tb, RKP, wU[2], RKP, DD, bw[2], vTb, DD, RKP);

    float* attn_out = (float*)d_out + (size_t)BB*SS*DD;
    attn_k<<<BH*32, 256, 0, stream>>>(hb[0], hb[1], vTb, attn_out, Ob);

    // output projection: O @ Vo^T -> T; T @ Uo^T + bo -> d_out (fp32)
    gemm_nt_k<0,0,0,0><<<dim3(MROWS/64, RKP/64), 256, 0, stream>>>(
        Ob, DD, wV[3], DD, RK, nullptr, Tb, RKP, DD);
    gemm_nt_k<0,1,1,0><<<dim3(MROWS/64, DD/64), 256, 0, stream>>>(
        Tb, RKP, wU[3], RKP, DD, bw[3], d_out, DD, RKP);
}

// Round 4
// 807.329 us; speedup vs baseline: 1.4477x; 1.4477x over previous
//
#include <hip/hip_runtime.h>
#include <stdint.h>

#define BB   2
#define SS   2048
#define DD   1024
#define NH   16
#define RK   204
#define RKP  256
#define HDIM 64
#define BH   (BB*NH)

typedef __attribute__((ext_vector_type(8))) short short8;
typedef __attribute__((ext_vector_type(4))) float f32x4;
typedef unsigned short u16;
typedef unsigned int   u32;

#define NEGBIG (-1e30f)

static __device__ __forceinline__ u16 f2bf(float f) {
    union { float f; u32 u; } v; v.f = f;
    u32 u = v.u;
    return (u16)((u + 0x7fffu + ((u >> 16) & 1u)) >> 16);  // RNE
}
static __device__ __forceinline__ u32 pack2(float lo, float hi) {
    return (u32)f2bf(lo) | ((u32)f2bf(hi) << 16);
}

// ---------------- conversion kernels ----------------
__global__ void cvt_bf16_k(const float* __restrict__ in, u16* __restrict__ out, int n4) {
    int i = blockIdx.x * blockDim.x + threadIdx.x;
    if (i < n4) {
        float4 f = ((const float4*)in)[i];
        u32 lo = pack2(f.x, f.y), hi = pack2(f.z, f.w);
        ((uint2*)out)[i] = make_uint2(lo, hi);
    }
}

// U (DD x RK) fp32 -> (DD x RKP) bf16, zero pad cols [RK,RKP)
__global__ void cvt_pad_u_k(const float* __restrict__ in, u16* __restrict__ out) {
    int i = blockIdx.x * blockDim.x + threadIdx.x;
    if (i >= DD * RKP) return;
    int row = i >> 8, col = i & (RKP - 1);
    out[i] = (col < RK) ? f2bf(in[row * RK + col]) : (u16)0;
}

// ---------------- NT GEMM: C[M x N] = A[M x K] * B[N x K]^T (+bias) ----------------
// OUT_VT: instead of C row-major, write vT[bh][hd][s] (V-head transpose) via LDS.
template<int A_F32, int OUT_F32, int HAS_BIAS, int OUT_VT>
__global__ __launch_bounds__(256)
void gemm_nt_k(const void* __restrict__ Ap, int lda,
               const u16* __restrict__ Bp, int ldb, int nrowsB,
               const float* __restrict__ bias,
               void* __restrict__ Cp, int ldc, int K)
{
    __shared__ __align__(16) u16 As[64*72];
    __shared__ __align__(16) u16 Bs[64*72];
    const int row0 = blockIdx.x * 64;
    const int col0 = blockIdx.y * 64;
    const int t = threadIdx.x;
    const int w = t >> 6, lane = t & 63, quad = lane >> 4, l16 = lane & 15;
    const int r = t >> 2, seg = t & 3;

    f32x4 acc0 = 0.f, acc1 = 0.f, acc2 = 0.f, acc3 = 0.f;

    for (int k0 = 0; k0 < K; k0 += 64) {
        __syncthreads();
        if (A_F32) {
            const float* ga = (const float*)Ap + (size_t)(row0 + r) * lda + k0 + seg*16;
            float4 f0 = ((const float4*)ga)[0];
            float4 f1 = ((const float4*)ga)[1];
            float4 f2 = ((const float4*)ga)[2];
            float4 f3 = ((const float4*)ga)[3];
            uint4 s0 = { pack2(f0.x,f0.y), pack2(f0.z,f0.w), pack2(f1.x,f1.y), pack2(f1.z,f1.w) };
            uint4 s1 = { pack2(f2.x,f2.y), pack2(f2.z,f2.w), pack2(f3.x,f3.y), pack2(f3.z,f3.w) };
            *(uint4*)(As + r*72 + seg*16)     = s0;
            *(uint4*)(As + r*72 + seg*16 + 8) = s1;
        } else {
            const u16* ga = (const u16*)Ap + (size_t)(row0 + r) * lda + k0 + seg*16;
            *(uint4*)(As + r*72 + seg*16)     = ((const uint4*)ga)[0];
            *(uint4*)(As + r*72 + seg*16 + 8) = ((const uint4*)ga)[1];
        }
        {
            uint4 b0 = {0,0,0,0}, b1 = {0,0,0,0};
            if (col0 + r < nrowsB) {
                const u16* gb = Bp + (size_t)(col0 + r) * ldb + k0 + seg*16;
                b0 = ((const uint4*)gb)[0];
                b1 = ((const uint4*)gb)[1];
            }
            *(uint4*)(Bs + r*72 + seg*16)     = b0;
            *(uint4*)(Bs + r*72 + seg*16 + 8) = b1;
        }
        __syncthreads();
        #pragma unroll
        for (int c = 0; c < 2; ++c) {
            short8 a = *(const short8*)(As + (w*16 + l16)*72 + c*32 + quad*8);
            short8 b0v = *(const short8*)(Bs + (0*16 + l16)*72 + c*32 + quad*8);
            acc0 = __builtin_amdgcn_mfma_f32_16x16x32_bf16(a, b0v, acc0, 0, 0, 0);
            short8 b1v = *(const short8*)(Bs + (1*16 + l16)*72 + c*32 + quad*8);
            acc1 = __builtin_amdgcn_mfma_f32_16x16x32_bf16(a, b1v, acc1, 0, 0, 0);
            short8 b2v = *(const short8*)(Bs + (2*16 + l16)*72 + c*32 + quad*8);
            acc2 = __builtin_amdgcn_mfma_f32_16x16x32_bf16(a, b2v, acc2, 0, 0, 0);
            short8 b3v = *(const short8*)(Bs + (3*16 + l16)*72 + c*32 + quad*8);
            acc3 = __builtin_amdgcn_mfma_f32_16x16x32_bf16(a, b3v, acc3, 0, 0, 0);
        }
    }

    if (OUT_VT) {
        // write V-head transpose directly: vT[(bh*HDIM + hd)*SS + s]
        // col0 is 64-aligned and HDIM==64 -> this tile is exactly one head's 64 dims.
        __syncthreads();   // all waves done reading As/Bs
        #pragma unroll
        for (int f = 0; f < 4; ++f) {
            f32x4 a = (f==0) ? acc0 : (f==1) ? acc1 : (f==2) ? acc2 : acc3;
            int col = f*16 + l16;           // hd within head
            float bv = HAS_BIAS ? bias[col0 + col] : 0.f;
            #pragma unroll
            for (int rg = 0; rg < 4; ++rg) {
                int rowl = w*16 + quad*4 + rg;   // s within tile
                As[col*72 + rowl] = f2bf(a[rg] + bv);   // As reused as [hd][s]
            }
        }
        __syncthreads();
        const int b_ = row0 >> 11;          // which batch (SS=2048 rows per batch)
        const int s0 = row0 & (SS - 1);
        const int h  = col0 >> 6;
        u16* dst = (u16*)Cp + ((size_t)((b_*NH + h)*HDIM + r))*SS + s0 + seg*16;
        ((uint4*)dst)[0] = *(const uint4*)(As + r*72 + seg*16);
        ((uint4*)dst)[1] = *(const uint4*)(As + r*72 + seg*16 + 8);
        return;
    }

    #pragma unroll
    for (int f = 0; f < 4; ++f) {
        f32x4 a = (f==0) ? acc0 : (f==1) ? acc1 : (f==2) ? acc2 : acc3;
        int col = col0 + f*16 + l16;
        float bv = HAS_BIAS ? bias[col] : 0.f;
        #pragma unroll
        for (int rg = 0; rg < 4; ++rg) {
            int rowg = row0 + w*16 + quad*4 + rg;
            float val = a[rg] + bv;
            if (col >= nrowsB) val = 0.f;
            if (OUT_F32) ((float*)Cp)[(size_t)rowg*ldc + col] = val;
            else         ((u16*)Cp)[(size_t)rowg*ldc + col]  = f2bf(val);
        }
    }
}

// ---------------- fused attention: phase1 m,l + phase2 attn write + O = P*V ----------------
#define QKT_8(sa0,sa1,sa2,sa3) do { \
    short8 b0 = *(const short8*)(Ks + (0*16 + l16)*72 + quad*8); \
    sa0 = __builtin_amdgcn_mfma_f32_16x16x32_bf16(q0, b0, sa0, 0,0,0); \
    short8 b0b = *(const short8*)(Ks + (0*16 + l16)*72 + 32 + quad*8); \
    sa0 = __builtin_amdgcn_mfma_f32_16x16x32_bf16(q1, b0b, sa0, 0,0,0); \
    short8 b1 = *(const short8*)(Ks + (1*16 + l16)*72 + quad*8); \
    sa1 = __builtin_amdgcn_mfma_f32_16x16x32_bf16(q0, b1, sa1, 0,0,0); \
    short8 b1b = *(const short8*)(Ks + (1*16 + l16)*72 + 32 + quad*8); \
    sa1 = __builtin_amdgcn_mfma_f32_16x16x32_bf16(q1, b1b, sa1, 0,0,0); \
    short8 b2 = *(const short8*)(Ks + (2*16 + l16)*72 + quad*8); \
    sa2 = __builtin_amdgcn_mfma_f32_16x16x32_bf16(q0, b2, sa2, 0,0,0); \
    short8 b2b = *(const short8*)(Ks + (2*16 + l16)*72 + 32 + quad*8); \
    sa2 = __builtin_amdgcn_mfma_f32_16x16x32_bf16(q1, b2b, sa2, 0,0,0); \
    short8 b3 = *(const short8*)(Ks + (3*16 + l16)*72 + quad*8); \
    sa3 = __builtin_amdgcn_mfma_f32_16x16x32_bf16(q0, b3, sa3, 0,0,0); \
    short8 b3b = *(const short8*)(Ks + (3*16 + l16)*72 + 32 + quad*8); \
    sa3 = __builtin_amdgcn_mfma_f32_16x16x32_bf16(q1, b3b, sa3, 0,0,0); \
} while (0)

__global__ __launch_bounds__(256)
void attn_k(const u16* __restrict__ qh, const u16* __restrict__ kh,
            const u16* __restrict__ vT,
            float* __restrict__ attn_out, u16* __restrict__ Ob)
{
    __shared__ __align__(16) u16 Ks[64*72];
    __shared__ __align__(16) u16 Vs[64*72];
    __shared__ __align__(16) u16 Ps[64*72];
    const int blk = blockIdx.x;          // bh*32 + qt
    const int qt = blk & 31, bh = blk >> 5;
    const int b_ = bh >> 4, h = bh & (NH - 1);
    const int qbase = qt * 64;
    const int t = threadIdx.x, w = t >> 6, lane = t & 63, quad = lane >> 4, l16 = lane & 15;
    const int r = t >> 2, seg = t & 3;
    const float scl = 0.125f;

    const u16* qrow = qh + (size_t)(b_*SS + qbase + w*16 + l16)*DD + h*HDIM;
    short8 q0 = *(const short8*)(qrow + quad*8);
    short8 q1 = *(const short8*)(qrow + 32 + quad*8);

    const u16* kstage = kh + (size_t)(b_*SS + r)*DD + h*HDIM + seg*16;
    const u16* vstage = vT + ((size_t)(bh*HDIM + r))*SS + seg*16;

    // ---------------- phase 1: per-lane online (m,l), merge once ----------------
    float m[4], l[4];
    #pragma unroll
    for (int rg = 0; rg < 4; ++rg) { m[rg] = NEGBIG; l[rg] = 0.f; }

    for (int kt = 0; kt <= qt; ++kt) {
        __syncthreads();
        {
            const u16* krow = kstage + (size_t)kt*64*DD;
            *(uint4*)(Ks + r*72 + seg*16)     = ((const uint4*)krow)[0];
            *(uint4*)(Ks + r*72 + seg*16 + 8) = ((const uint4*)krow)[1];
        }
        __syncthreads();

        f32x4 sa0 = 0.f, sa1 = 0.f, sa2 = 0.f, sa3 = 0.f;
        QKT_8(sa0, sa1, sa2, sa3);

        if (kt < qt) {
            #pragma unroll
            for (int rg = 0; rg < 4; ++rg) {
                float v0 = sa0[rg]*scl, v1 = sa1[rg]*scl, v2 = sa2[rg]*scl, v3 = sa3[rg]*scl;
                float m4 = fmaxf(fmaxf(v0, v1), fmaxf(v2, v3));
                float nm = fmaxf(m[rg], m4);
                l[rg] = l[rg]*__expf(m[rg]-nm)
                      + (__expf(v0-nm)+__expf(v1-nm)) + (__expf(v2-nm)+__expf(v3-nm));
                m[rg] = nm;
            }
        } else {
            int key0 = kt*64 + l16;
            #pragma unroll
            for (int rg = 0; rg < 4; ++rg) {
                int qg = qbase + w*16 + quad*4 + rg;
                bool c0 = (key0      <= qg), c1 = (key0 + 16 <= qg);
                bool c2 = (key0 + 32 <= qg), c3 = (key0 + 48 <= qg);
                float v0 = c0 ? sa0[rg]*scl : NEGBIG;
                float v1 = c1 ? sa1[rg]*scl : NEGBIG;
                float v2 = c2 ? sa2[rg]*scl : NEGBIG;
                float v3 = c3 ? sa3[rg]*scl : NEGBIG;
                float m4 = fmaxf(fmaxf(v0, v1), fmaxf(v2, v3));
                float nm = fmaxf(m[rg], m4);
                float e0 = c0 ? __expf(v0-nm) : 0.f;
                float e1 = c1 ? __expf(v1-nm) : 0.f;
                float e2 = c2 ? __expf(v2-nm) : 0.f;
                float e3 = c3 ? __expf(v3-nm) : 0.f;
                float corr = (m[rg] > NEGBIG) ? __expf(m[rg]-nm) : 0.f;
                l[rg] = l[rg]*corr + (e0+e1) + (e2+e3);
                m[rg] = nm;
            }
        }
    }

    // 16-lane merge; afterwards every lane holds its rows' final (m,l)
    #pragma unroll
    for (int rg = 0; rg < 4; ++rg) {
        #pragma unroll
        for (int d = 1; d < 16; d <<= 1) {
            float mo = __shfl_xor(m[rg], d);
            float lo = __shfl_xor(l[rg], d);
            float nm = fmaxf(m[rg], mo);
            l[rg] = l[rg]*__expf(m[rg]-nm) + lo*__expf(mo-nm);
            m[rg] = nm;
        }
    }
    float mr[4], rl[4];
    #pragma unroll
    for (int rg = 0; rg < 4; ++rg) { mr[rg] = m[rg]; rl[rg] = 1.f / l[rg]; }

    // ---------------- phase 2: P write + O = P*V ----------------
    f32x4 oa0 = 0.f, oa1 = 0.f, oa2 = 0.f, oa3 = 0.f;
    float* attn_base = attn_out + (size_t)bh * SS * SS;
    float* rp0 = attn_base + (size_t)(qbase + w*16 + quad*4 + 0)*SS + l16;
    float* rp1 = attn_base + (size_t)(qbase + w*16 + quad*4 + 1)*SS + l16;
    float* rp2 = attn_base + (size_t)(qbase + w*16 + quad*4 + 2)*SS + l16;
    float* rp3 = attn_base + (size_t)(qbase + w*16 + quad*4 + 3)*SS + l16;

    for (int kt = 0; kt <= qt; ++kt) {
        __syncthreads();
        {
            const u16* krow = kstage + (size_t)kt*64*DD;
            *(uint4*)(Ks + r*72 + seg*16)     = ((const uint4*)krow)[0];
            *(uint4*)(Ks + r*72 + seg*16 + 8) = ((const uint4*)krow)[1];
            const u16* vrow = vstage + kt*64;
            *(uint4*)(Vs + r*72 + seg*16)     = ((const uint4*)vrow)[0];
            *(uint4*)(Vs + r*72 + seg*16 + 8) = ((const uint4*)vrow)[1];
        }
        __syncthreads();

        f32x4 sa0 = 0.f, sa1 = 0.f, sa2 = 0.f, sa3 = 0.f;
        QKT_8(sa0, sa1, sa2, sa3);

        if (kt < qt) {
            #pragma unroll
            for (int f = 0; f < 4; ++f) {
                f32x4 sv = (f==0) ? sa0 : (f==1) ? sa1 : (f==2) ? sa2 : sa3;
                float p0 = __expf(sv[0]*scl - mr[0]) * rl[0];
                float p1 = __expf(sv[1]*scl - mr[1]) * rl[1];
                float p2 = __expf(sv[2]*scl - mr[2]) * rl[2];
                float p3 = __expf(sv[3]*scl - mr[3]) * rl[3];
                rp0[f*16] = p0;
                rp1[f*16] = p1;
                rp2[f*16] = p2;
                rp3[f*16] = p3;
                Ps[(w*16 + quad*4 + 0)*72 + f*16 + l16] = f2bf(p0);
                Ps[(w*16 + quad*4 + 1)*72 + f*16 + l16] = f2bf(p1);
                Ps[(w*16 + quad*4 + 2)*72 + f*16 + l16] = f2bf(p2);
                Ps[(w*16 + quad*4 + 3)*72 + f*16 + l16] = f2bf(p3);
            }
        } else {
            int kbase = kt*64;
            #pragma unroll
            for (int f = 0; f < 4; ++f) {
                f32x4 sv = (f==0) ? sa0 : (f==1) ? sa1 : (f==2) ? sa2 : sa3;
                int key = kbase + f*16 + l16;
                #pragma unroll
                for (int rg = 0; rg < 4; ++rg) {
                    int qg = qbase + w*16 + quad*4 + rg;
                    float p = (key <= qg) ? __expf(sv[rg]*scl - mr[rg]) * rl[rg] : 0.f;
                    float* rp = (rg==0) ? rp0 : (rg==1) ? rp1 : (rg==2) ? rp2 : rp3;
                    rp[f*16] = p;
                    Ps[(w*16 + quad*4 + rg)*72 + f*16 + l16] = f2bf(p);
                }
            }
        }
        rp0 += 64; rp1 += 64; rp2 += 64; rp3 += 64;

        // Ps rows are wave-private (wave w writes and reads rows w*16..w*16+15);
        // per-wave LDS pipe is in-order — compiler-level fence only, no barrier.
        asm volatile("" ::: "memory");

        // O += P * V
        #pragma unroll
        for (int c = 0; c < 2; ++c) {
            short8 pa = *(const short8*)(Ps + (w*16 + l16)*72 + c*32 + quad*8);
            short8 v0 = *(const short8*)(Vs + (0*16 + l16)*72 + c*32 + quad*8);
            oa0 = __builtin_amdgcn_mfma_f32_16x16x32_bf16(pa, v0, oa0, 0,0,0);
            short8 v1 = *(const short8*)(Vs + (1*16 + l16)*72 + c*32 + quad*8);
            oa1 = __builtin_amdgcn_mfma_f32_16x16x32_bf16(pa, v1, oa1, 0,0,0);
            short8 v2 = *(const short8*)(Vs + (2*16 + l16)*72 + c*32 + quad*8);
            oa2 = __builtin_amdgcn_mfma_f32_16x16x32_bf16(pa, v2, oa2, 0,0,0);
            short8 v3 = *(const short8*)(Vs + (3*16 + l16)*72 + c*32 + quad*8);
            oa3 = __builtin_amdgcn_mfma_f32_16x16x32_bf16(pa, v3, oa3, 0,0,0);
        }
    }

    // fully-masked upper tiles: explicit zeros (d_out is poisoned)
    for (int kt = qt + 1; kt < 32; ++kt) {
        int kbase = kt * 64;
        f32x4 z = 0.f;
        f32x4* p = (f32x4*)(attn_base + (size_t)(qbase + r)*SS + kbase + seg*16);
        p[0] = z; p[1] = z; p[2] = z; p[3] = z;
    }

    #pragma unroll
    for (int f = 0; f < 4; ++f) {
        f32x4 ov = (f==0) ? oa0 : (f==1) ? oa1 : (f==2) ? oa2 : oa3;
        #pragma unroll
        for (int rg = 0; rg < 4; ++rg) {
            int qg = qbase + w*16 + quad*4 + rg;
            Ob[(size_t)(b_*SS + qg)*DD + h*HDIM + f*16 + l16] = f2bf(ov[rg]);
        }
    }
}

// ---------------- launch ----------------
extern "C" void kernel_launch(void* const* d_in, const int* in_sizes, int n_in,
                              void* d_out, int out_size, void* d_ws, size_t ws_size,
                              hipStream_t stream)
{
    const float* xs[3] = { (const float*)d_in[0], (const float*)d_in[1], (const float*)d_in[2] };
    const float* Vw[4] = { (const float*)d_in[3], (const float*)d_in[6], (const float*)d_in[9],  (const float*)d_in[12] };
    const float* Uw[4] = { (const float*)d_in[4], (const float*)d_in[7], (const float*)d_in[10], (const float*)d_in[13] };
    const float* bw[4] = { (const float*)d_in[5], (const float*)d_in[8], (const float*)d_in[11], (const float*)d_in[14] };

    char* ws = (char*)d_ws;
    size_t off = 0;
    auto alloc = [&](size_t bytes) -> char* {
        char* p = ws + off;
        off += (bytes + 255) & ~(size_t)255;
        return p;
    };
    u16* wV[4]; for (int i = 0; i < 4; ++i) wV[i] = (u16*)alloc((size_t)RK*DD*2);
    u16* wU[4]; for (int i = 0; i < 4; ++i) wU[i] = (u16*)alloc((size_t)DD*RKP*2);
    u16* Tb  = (u16*)alloc((size_t)BB*SS*RKP*2);
    u16* hb[2]; for (int i = 0; i < 2; ++i) hb[i] = (u16*)alloc((size_t)BB*SS*DD*2);
    u16* vTb = (u16*)alloc((size_t)BB*SS*DD*2);
    u16* Ob  = (u16*)alloc((size_t)BB*SS*DD*2);
    (void)ws_size; (void)in_sizes; (void)n_in; (void)out_size;

    // weight conversions
    for (int i = 0; i < 4; ++i)
        cvt_bf16_k<<<(RK*DD/4 + 255)/256, 256, 0, stream>>>(Vw[i], wV[i], RK*DD/4);
    for (int i = 0; i < 4; ++i)
        cvt_pad_u_k<<<(DD*RKP + 255)/256, 256, 0, stream>>>(Uw[i], wU[i]);

    const int MROWS = BB*SS;           // 4096
    // q,k projections: X @ V^T -> T[4096x256 padded]; T @ U^T + b -> heads bf16
    for (int p = 0; p < 2; ++p) {
        gemm_nt_k<1,0,0,0><<<dim3(MROWS/64, RKP/64), 256, 0, stream>>>(
            xs[p], DD, wV[p], DD, RK, nullptr, Tb, RKP, DD);
        gemm_nt_k<0,0,1,0><<<dim3(MROWS/64, DD/64), 256, 0, stream>>>(
            Tb, RKP, wU[p], RKP, DD, bw[p], hb[p], DD, RKP);
    }
    // v projection: second GEMM writes vT[bh][hd][s] directly (transposed epilogue)
    gemm_nt_k<1,0,0,0><<<dim3(MROWS/64, RKP/64), 256, 0, stream>>>(
        xs[2], DD, wV[2], DD, RK, nullptr, Tb, RKP, DD);
    gemm_nt_k<0,0,1,1><<<dim3(MROWS/64, DD/64), 256, 0, stream>>>(
        Tb, RKP, wU[2], RKP, DD, bw[2], vTb, DD, RKP);

    float* attn_out = (float*)d_out + (size_t)BB*SS*DD;
    attn_k<<<BH*32, 256, 0, stream>>>(hb[0], hb[1], vTb, attn_out, Ob);

    // output projection: O @ Vo^T -> T; T @ Uo^T + bo -> d_out (fp32)
    gemm_nt_k<0,0,0,0><<<dim3(MROWS/64, RKP/64), 256, 0, stream>>>(
        Ob, DD, wV[3], DD, RK, nullptr, Tb, RKP, DD);
    gemm_nt_k<0,1,1,0><<<dim3(MROWS/64, DD/64), 256, 0, stream>>>(
        Tb, RKP, wU[3], RKP, DD, bw[3], d_out, DD, RKP);
}

// Round 5
// 754.966 us; speedup vs baseline: 1.5481x; 1.0694x over previous
//
#include <hip/hip_runtime.h>
#include <stdint.h>

#define BB   2
#define SS   2048
#define DD   1024
#define NH   16
#define RK   204
#define RKP  256
#define HDIM 64
#define BH   (BB*NH)

typedef __attribute__((ext_vector_type(8))) short short8;
typedef __attribute__((ext_vector_type(4))) float f32x4;
typedef unsigned short u16;
typedef unsigned int   u32;

#define NEGBIG (-1e30f)
#define LOG2E  1.4426950408889634f

static __device__ __forceinline__ u32 cvtpk(float lo, float hi) {
    u32 r; asm("v_cvt_pk_bf16_f32 %0, %1, %2" : "=v"(r) : "v"(lo), "v"(hi)); return r;
}
static __device__ __forceinline__ u16 f2bf(float f) { return (u16)cvtpk(f, f); }
static __device__ __forceinline__ u32 pack2(float lo, float hi) { return cvtpk(lo, hi); }
static __device__ __forceinline__ float exp2_hw(float x) {
    float r; asm("v_exp_f32 %0, %1" : "=v"(r) : "v"(x)); return r;
}

// ---------------- batched conversion kernels ----------------
struct C4 { const float *s0, *s1, *s2, *s3; u16 *d0, *d1, *d2, *d3; };

__global__ void cvt_bf16_b4(C4 c, int n4) {
    int y = blockIdx.y;
    const float* in = (y==0)?c.s0:(y==1)?c.s1:(y==2)?c.s2:c.s3;
    u16* out = (y==0)?c.d0:(y==1)?c.d1:(y==2)?c.d2:c.d3;
    int i = blockIdx.x * blockDim.x + threadIdx.x;
    if (i < n4) {
        float4 f = ((const float4*)in)[i];
        ((uint2*)out)[i] = make_uint2(pack2(f.x, f.y), pack2(f.z, f.w));
    }
}

// U (DD x RK) fp32 -> (DD x RKP) bf16, zero pad cols [RK,RKP)
__global__ void cvt_pad_b4(C4 c, int n) {
    int y = blockIdx.y;
    const float* in = (y==0)?c.s0:(y==1)?c.s1:(y==2)?c.s2:c.s3;
    u16* out = (y==0)?c.d0:(y==1)?c.d1:(y==2)?c.d2:c.d3;
    int i = blockIdx.x * blockDim.x + threadIdx.x;
    if (i >= n) return;
    int row = i >> 8, col = i & (RKP - 1);
    out[i] = (col < RK) ? f2bf(in[row * RK + col]) : (u16)0;
}

// ---------------- z-batched NT GEMM: C[M x N] = A[M x K] * B[N x K]^T (+bias) ----------------
// VT_LAST: z==2 writes vT[bh][hd][s] via LDS transpose. QSC: z==0 output scaled by 0.125.
struct B3 {
    const void *A0, *A1, *A2;
    const u16  *B0, *B1, *B2;
    const float *bb0, *bb1, *bb2;
    void *C0, *C1, *C2;
};

template<int A_F32, int OUT_F32, int HAS_BIAS, int VT_LAST, int QSC>
__global__ __launch_bounds__(256)
void gemm_nt_k(B3 g, int lda, int ldb, int nrowsB, int ldc, int K)
{
    const int z = blockIdx.z;
    const void* Ap  = (z==0)?g.A0:(z==1)?g.A1:g.A2;
    const u16*  Bp  = (z==0)?g.B0:(z==1)?g.B1:g.B2;
    const float* bias = (z==0)?g.bb0:(z==1)?g.bb1:g.bb2;
    void* Cp = (z==0)?g.C0:(z==1)?g.C1:g.C2;

    __shared__ __align__(16) u16 As[64*72];
    __shared__ __align__(16) u16 Bs[64*72];
    const int row0 = blockIdx.x * 64;
    const int col0 = blockIdx.y * 64;
    const int t = threadIdx.x;
    const int w = t >> 6, lane = t & 63, quad = lane >> 4, l16 = lane & 15;
    const int r = t >> 2, seg = t & 3;

    f32x4 acc0 = 0.f, acc1 = 0.f, acc2 = 0.f, acc3 = 0.f;

    for (int k0 = 0; k0 < K; k0 += 64) {
        __syncthreads();
        if (A_F32) {
            const float* ga = (const float*)Ap + (size_t)(row0 + r) * lda + k0 + seg*16;
            float4 f0 = ((const float4*)ga)[0];
            float4 f1 = ((const float4*)ga)[1];
            float4 f2 = ((const float4*)ga)[2];
            float4 f3 = ((const float4*)ga)[3];
            uint4 s0 = { pack2(f0.x,f0.y), pack2(f0.z,f0.w), pack2(f1.x,f1.y), pack2(f1.z,f1.w) };
            uint4 s1 = { pack2(f2.x,f2.y), pack2(f2.z,f2.w), pack2(f3.x,f3.y), pack2(f3.z,f3.w) };
            *(uint4*)(As + r*72 + seg*16)     = s0;
            *(uint4*)(As + r*72 + seg*16 + 8) = s1;
        } else {
            const u16* ga = (const u16*)Ap + (size_t)(row0 + r) * lda + k0 + seg*16;
            *(uint4*)(As + r*72 + seg*16)     = ((const uint4*)ga)[0];
            *(uint4*)(As + r*72 + seg*16 + 8) = ((const uint4*)ga)[1];
        }
        {
            uint4 b0 = {0,0,0,0}, b1 = {0,0,0,0};
            if (col0 + r < nrowsB) {
                const u16* gb = Bp + (size_t)(col0 + r) * ldb + k0 + seg*16;
                b0 = ((const uint4*)gb)[0];
                b1 = ((const uint4*)gb)[1];
            }
            *(uint4*)(Bs + r*72 + seg*16)     = b0;
            *(uint4*)(Bs + r*72 + seg*16 + 8) = b1;
        }
        __syncthreads();
        #pragma unroll
        for (int c = 0; c < 2; ++c) {
            short8 a = *(const short8*)(As + (w*16 + l16)*72 + c*32 + quad*8);
            short8 b0v = *(const short8*)(Bs + (0*16 + l16)*72 + c*32 + quad*8);
            acc0 = __builtin_amdgcn_mfma_f32_16x16x32_bf16(a, b0v, acc0, 0, 0, 0);
            short8 b1v = *(const short8*)(Bs + (1*16 + l16)*72 + c*32 + quad*8);
            acc1 = __builtin_amdgcn_mfma_f32_16x16x32_bf16(a, b1v, acc1, 0, 0, 0);
            short8 b2v = *(const short8*)(Bs + (2*16 + l16)*72 + c*32 + quad*8);
            acc2 = __builtin_amdgcn_mfma_f32_16x16x32_bf16(a, b2v, acc2, 0, 0, 0);
            short8 b3v = *(const short8*)(Bs + (3*16 + l16)*72 + c*32 + quad*8);
            acc3 = __builtin_amdgcn_mfma_f32_16x16x32_bf16(a, b3v, acc3, 0, 0, 0);
        }
    }

    if (VT_LAST && z == 2) {
        // write V-head transpose directly: vT[(bh*HDIM + hd)*SS + s]
        __syncthreads();   // all waves done reading As/Bs
        #pragma unroll
        for (int f = 0; f < 4; ++f) {
            f32x4 a = (f==0) ? acc0 : (f==1) ? acc1 : (f==2) ? acc2 : acc3;
            int col = f*16 + l16;           // hd within head
            float bv = HAS_BIAS ? bias[col0 + col] : 0.f;
            #pragma unroll
            for (int rg = 0; rg < 4; ++rg) {
                int rowl = w*16 + quad*4 + rg;   // s within tile
                As[col*72 + rowl] = f2bf(a[rg] + bv);   // As reused as [hd][s]
            }
        }
        __syncthreads();
        const int b_ = row0 >> 11;
        const int s0 = row0 & (SS - 1);
        const int h  = col0 >> 6;
        u16* dst = (u16*)Cp + ((size_t)((b_*NH + h)*HDIM + r))*SS + s0 + seg*16;
        ((uint4*)dst)[0] = *(const uint4*)(As + r*72 + seg*16);
        ((uint4*)dst)[1] = *(const uint4*)(As + r*72 + seg*16 + 8);
        return;
    }

    const float osc = (QSC && z == 0) ? 0.125f : 1.f;
    #pragma unroll
    for (int f = 0; f < 4; ++f) {
        f32x4 a = (f==0) ? acc0 : (f==1) ? acc1 : (f==2) ? acc2 : acc3;
        int col = col0 + f*16 + l16;
        float bv = HAS_BIAS ? bias[col] : 0.f;
        #pragma unroll
        for (int rg = 0; rg < 4; ++rg) {
            int rowg = row0 + w*16 + quad*4 + rg;
            float val = (a[rg] + bv) * osc;
            if (col >= nrowsB) val = 0.f;
            if (OUT_F32) ((float*)Cp)[(size_t)rowg*ldc + col] = val;
            else         ((u16*)Cp)[(size_t)rowg*ldc + col]  = f2bf(val);
        }
    }
}

// ---------------- fused attention ----------------
#define QKT_8(BUF,sa0,sa1,sa2,sa3) do { \
    short8 b0 = *(const short8*)(BUF + (0*16 + l16)*72 + quad*8); \
    sa0 = __builtin_amdgcn_mfma_f32_16x16x32_bf16(q0, b0, sa0, 0,0,0); \
    short8 b0b = *(const short8*)(BUF + (0*16 + l16)*72 + 32 + quad*8); \
    sa0 = __builtin_amdgcn_mfma_f32_16x16x32_bf16(q1, b0b, sa0, 0,0,0); \
    short8 b1 = *(const short8*)(BUF + (1*16 + l16)*72 + quad*8); \
    sa1 = __builtin_amdgcn_mfma_f32_16x16x32_bf16(q0, b1, sa1, 0,0,0); \
    short8 b1b = *(const short8*)(BUF + (1*16 + l16)*72 + 32 + quad*8); \
    sa1 = __builtin_amdgcn_mfma_f32_16x16x32_bf16(q1, b1b, sa1, 0,0,0); \
    short8 b2 = *(const short8*)(BUF + (2*16 + l16)*72 + quad*8); \
    sa2 = __builtin_amdgcn_mfma_f32_16x16x32_bf16(q0, b2, sa2, 0,0,0); \
    short8 b2b = *(const short8*)(BUF + (2*16 + l16)*72 + 32 + quad*8); \
    sa2 = __builtin_amdgcn_mfma_f32_16x16x32_bf16(q1, b2b, sa2, 0,0,0); \
    short8 b3 = *(const short8*)(BUF + (3*16 + l16)*72 + quad*8); \
    sa3 = __builtin_amdgcn_mfma_f32_16x16x32_bf16(q0, b3, sa3, 0,0,0); \
    short8 b3b = *(const short8*)(BUF + (3*16 + l16)*72 + 32 + quad*8); \
    sa3 = __builtin_amdgcn_mfma_f32_16x16x32_bf16(q1, b3b, sa3, 0,0,0); \
} while (0)

// phase-1 online update, interior tile (no masking). All in exp2 domain.
static __device__ __forceinline__ void p1_int(
    const f32x4& sa0, const f32x4& sa1, const f32x4& sa2, const f32x4& sa3,
    float* m, float* l)
{
    #pragma unroll
    for (int rg = 0; rg < 4; ++rg) {
        float v0 = sa0[rg], v1 = sa1[rg], v2 = sa2[rg], v3 = sa3[rg];
        float m4 = fmaxf(fmaxf(v0, v1), fmaxf(v2, v3));
        float nm = fmaxf(m[rg], m4);
        float nm2 = nm * LOG2E;
        float e = exp2_hw(__builtin_fmaf(v0, LOG2E, -nm2)) + exp2_hw(__builtin_fmaf(v1, LOG2E, -nm2))
                + exp2_hw(__builtin_fmaf(v2, LOG2E, -nm2)) + exp2_hw(__builtin_fmaf(v3, LOG2E, -nm2));
        float corr = exp2_hw(__builtin_fmaf(m[rg], LOG2E, -nm2));
        l[rg] = l[rg]*corr + e;
        m[rg] = nm;
    }
}
// phase-1 online update, diagonal tile (causal masking; explicit zero-selects).
static __device__ __forceinline__ void p1_diag(
    const f32x4& sa0, const f32x4& sa1, const f32x4& sa2, const f32x4& sa3,
    float* m, float* l, int key0, int qg0)
{
    #pragma unroll
    for (int rg = 0; rg < 4; ++rg) {
        int qg = qg0 + rg;
        bool c0 = (key0      <= qg), c1 = (key0 + 16 <= qg);
        bool c2 = (key0 + 32 <= qg), c3 = (key0 + 48 <= qg);
        float v0 = c0 ? sa0[rg] : NEGBIG;
        float v1 = c1 ? sa1[rg] : NEGBIG;
        float v2 = c2 ? sa2[rg] : NEGBIG;
        float v3 = c3 ? sa3[rg] : NEGBIG;
        float m4 = fmaxf(fmaxf(v0, v1), fmaxf(v2, v3));
        float nm = fmaxf(m[rg], m4);
        float nm2 = nm * LOG2E;
        float e0 = c0 ? exp2_hw(__builtin_fmaf(v0, LOG2E, -nm2)) : 0.f;
        float e1 = c1 ? exp2_hw(__builtin_fmaf(v1, LOG2E, -nm2)) : 0.f;
        float e2 = c2 ? exp2_hw(__builtin_fmaf(v2, LOG2E, -nm2)) : 0.f;
        float e3 = c3 ? exp2_hw(__builtin_fmaf(v3, LOG2E, -nm2)) : 0.f;
        float corr = (m[rg] > NEGBIG) ? exp2_hw(__builtin_fmaf(m[rg], LOG2E, -nm2)) : 0.f;
        l[rg] = l[rg]*corr + (e0+e1) + (e2+e3);
        m[rg] = nm;
    }
}

__global__ __launch_bounds__(256)
void attn_k(const u16* __restrict__ qh, const u16* __restrict__ kh,
            const u16* __restrict__ vT,
            float* __restrict__ attn_out, u16* __restrict__ Ob)
{
    __shared__ __align__(16) u16 Ks[64*72];
    __shared__ __align__(16) u16 Vs[64*72];
    __shared__ __align__(16) u16 Ps[64*72];
    const int blk = blockIdx.x;          // bh*32 + qt
    const int qt = blk & 31, bh = blk >> 5;
    const int b_ = bh >> 4, h = bh & (NH - 1);
    const int qbase = qt * 64;
    const int t = threadIdx.x, w = t >> 6, lane = t & 63, quad = lane >> 4, l16 = lane & 15;
    const int r = t >> 2, seg = t & 3;

    // q is pre-scaled by 1/8 at the projection epilogue (exact power-of-2)
    const u16* qrow = qh + (size_t)(b_*SS + qbase + w*16 + l16)*DD + h*HDIM;
    short8 q0 = *(const short8*)(qrow + quad*8);
    short8 q1 = *(const short8*)(qrow + 32 + quad*8);

    const u16* kstage = kh + (size_t)(b_*SS + r)*DD + h*HDIM + seg*16;
    const u16* vstage = vT + ((size_t)(bh*HDIM + r))*SS + seg*16;
    const int qg0 = qbase + w*16 + quad*4;

    // ---------------- phase 1: per-lane online (m,l), double-tile staged ----------------
    float m[4], l[4];
    #pragma unroll
    for (int rg = 0; rg < 4; ++rg) { m[rg] = NEGBIG; l[rg] = 0.f; }

    for (int kt0 = 0; kt0 <= qt; kt0 += 2) {
        const bool two = (kt0 + 1) <= qt;
        __syncthreads();
        {
            const u16* krow = kstage + (size_t)kt0*64*DD;
            *(uint4*)(Ks + r*72 + seg*16)     = ((const uint4*)krow)[0];
            *(uint4*)(Ks + r*72 + seg*16 + 8) = ((const uint4*)krow)[1];
            if (two) {
                const u16* krow2 = krow + (size_t)64*DD;
                *(uint4*)(Vs + r*72 + seg*16)     = ((const uint4*)krow2)[0];
                *(uint4*)(Vs + r*72 + seg*16 + 8) = ((const uint4*)krow2)[1];
            }
        }
        __syncthreads();
        {
            f32x4 sa0 = 0.f, sa1 = 0.f, sa2 = 0.f, sa3 = 0.f;
            QKT_8(Ks, sa0, sa1, sa2, sa3);
            if (kt0 < qt) p1_int(sa0, sa1, sa2, sa3, m, l);
            else          p1_diag(sa0, sa1, sa2, sa3, m, l, kt0*64 + l16, qg0);
        }
        if (two) {
            f32x4 sa0 = 0.f, sa1 = 0.f, sa2 = 0.f, sa3 = 0.f;
            QKT_8(Vs, sa0, sa1, sa2, sa3);
            if (kt0 + 1 < qt) p1_int(sa0, sa1, sa2, sa3, m, l);
            else              p1_diag(sa0, sa1, sa2, sa3, m, l, (kt0+1)*64 + l16, qg0);
        }
    }

    // 16-lane merge; afterwards every lane holds its rows' final (m,l)
    #pragma unroll
    for (int rg = 0; rg < 4; ++rg) {
        #pragma unroll
        for (int d = 1; d < 16; d <<= 1) {
            float mo = __shfl_xor(m[rg], d);
            float lo = __shfl_xor(l[rg], d);
            float nm = fmaxf(m[rg], mo);
            l[rg] = l[rg]*__expf(m[rg]-nm) + lo*__expf(mo-nm);
            m[rg] = nm;
        }
    }
    float mneg2[4], rl[4];
    #pragma unroll
    for (int rg = 0; rg < 4; ++rg) { mneg2[rg] = -(m[rg]*LOG2E); rl[rg] = 1.f / l[rg]; }

    // ---------------- phase 2: P write + O = P*V ----------------
    f32x4 oa0 = 0.f, oa1 = 0.f, oa2 = 0.f, oa3 = 0.f;
    float* attn_base = attn_out + (size_t)bh * SS * SS;
    float* rp0 = attn_base + (size_t)(qg0 + 0)*SS + l16;
    float* rp1 = attn_base + (size_t)(qg0 + 1)*SS + l16;
    float* rp2 = attn_base + (size_t)(qg0 + 2)*SS + l16;
    float* rp3 = attn_base + (size_t)(qg0 + 3)*SS + l16;
    const int psrow = w*16 + quad*4;

    for (int kt = 0; kt <= qt; ++kt) {
        __syncthreads();
        {
            const u16* krow = kstage + (size_t)kt*64*DD;
            *(uint4*)(Ks + r*72 + seg*16)     = ((const uint4*)krow)[0];
            *(uint4*)(Ks + r*72 + seg*16 + 8) = ((const uint4*)krow)[1];
            const u16* vrow = vstage + kt*64;
            *(uint4*)(Vs + r*72 + seg*16)     = ((const uint4*)vrow)[0];
            *(uint4*)(Vs + r*72 + seg*16 + 8) = ((const uint4*)vrow)[1];
        }
        __syncthreads();

        f32x4 sa0 = 0.f, sa1 = 0.f, sa2 = 0.f, sa3 = 0.f;
        QKT_8(Ks, sa0, sa1, sa2, sa3);

        if (kt < qt) {
            #pragma unroll
            for (int f = 0; f < 4; ++f) {
                f32x4 sv = (f==0) ? sa0 : (f==1) ? sa1 : (f==2) ? sa2 : sa3;
                float p0 = exp2_hw(__builtin_fmaf(sv[0], LOG2E, mneg2[0])) * rl[0];
                float p1 = exp2_hw(__builtin_fmaf(sv[1], LOG2E, mneg2[1])) * rl[1];
                float p2 = exp2_hw(__builtin_fmaf(sv[2], LOG2E, mneg2[2])) * rl[2];
                float p3 = exp2_hw(__builtin_fmaf(sv[3], LOG2E, mneg2[3])) * rl[3];
                rp0[f*16] = p0; rp1[f*16] = p1; rp2[f*16] = p2; rp3[f*16] = p3;
                u32 pk01 = cvtpk(p0, p1), pk23 = cvtpk(p2, p3);
                Ps[(psrow+0)*72 + f*16 + l16] = (u16)pk01;
                Ps[(psrow+1)*72 + f*16 + l16] = (u16)(pk01 >> 16);
                Ps[(psrow+2)*72 + f*16 + l16] = (u16)pk23;
                Ps[(psrow+3)*72 + f*16 + l16] = (u16)(pk23 >> 16);
            }
        } else {
            int kbase = kt*64;
            #pragma unroll
            for (int f = 0; f < 4; ++f) {
                f32x4 sv = (f==0) ? sa0 : (f==1) ? sa1 : (f==2) ? sa2 : sa3;
                int key = kbase + f*16 + l16;
                float p0 = (key <= qg0+0) ? exp2_hw(__builtin_fmaf(sv[0], LOG2E, mneg2[0]))*rl[0] : 0.f;
                float p1 = (key <= qg0+1) ? exp2_hw(__builtin_fmaf(sv[1], LOG2E, mneg2[1]))*rl[1] : 0.f;
                float p2 = (key <= qg0+2) ? exp2_hw(__builtin_fmaf(sv[2], LOG2E, mneg2[2]))*rl[2] : 0.f;
                float p3 = (key <= qg0+3) ? exp2_hw(__builtin_fmaf(sv[3], LOG2E, mneg2[3]))*rl[3] : 0.f;
                rp0[f*16] = p0; rp1[f*16] = p1; rp2[f*16] = p2; rp3[f*16] = p3;
                u32 pk01 = cvtpk(p0, p1), pk23 = cvtpk(p2, p3);
                Ps[(psrow+0)*72 + f*16 + l16] = (u16)pk01;
                Ps[(psrow+1)*72 + f*16 + l16] = (u16)(pk01 >> 16);
                Ps[(psrow+2)*72 + f*16 + l16] = (u16)pk23;
                Ps[(psrow+3)*72 + f*16 + l16] = (u16)(pk23 >> 16);
            }
        }
        rp0 += 64; rp1 += 64; rp2 += 64; rp3 += 64;

        // Ps rows are wave-private (wave w writes and reads rows w*16..w*16+15);
        // per-wave LDS pipe is in-order — compiler-level fence only, no barrier.
        asm volatile("" ::: "memory");

        // O += P * V
        #pragma unroll
        for (int c = 0; c < 2; ++c) {
            short8 pa = *(const short8*)(Ps + (w*16 + l16)*72 + c*32 + quad*8);
            short8 v0 = *(const short8*)(Vs + (0*16 + l16)*72 + c*32 + quad*8);
            oa0 = __builtin_amdgcn_mfma_f32_16x16x32_bf16(pa, v0, oa0, 0,0,0);
            short8 v1 = *(const short8*)(Vs + (1*16 + l16)*72 + c*32 + quad*8);
            oa1 = __builtin_amdgcn_mfma_f32_16x16x32_bf16(pa, v1, oa1, 0,0,0);
            short8 v2 = *(const short8*)(Vs + (2*16 + l16)*72 + c*32 + quad*8);
            oa2 = __builtin_amdgcn_mfma_f32_16x16x32_bf16(pa, v2, oa2, 0,0,0);
            short8 v3 = *(const short8*)(Vs + (3*16 + l16)*72 + c*32 + quad*8);
            oa3 = __builtin_amdgcn_mfma_f32_16x16x32_bf16(pa, v3, oa3, 0,0,0);
        }
    }

    // fully-masked upper tiles: explicit zeros (d_out is poisoned)
    for (int kt = qt + 1; kt < 32; ++kt) {
        int kbase = kt * 64;
        f32x4 z = 0.f;
        f32x4* p = (f32x4*)(attn_base + (size_t)(qbase + r)*SS + kbase + seg*16);
        p[0] = z; p[1] = z; p[2] = z; p[3] = z;
    }

    #pragma unroll
    for (int f = 0; f < 4; ++f) {
        f32x4 ov = (f==0) ? oa0 : (f==1) ? oa1 : (f==2) ? oa2 : oa3;
        #pragma unroll
        for (int rg = 0; rg < 4; ++rg) {
            int qg = qg0 + rg;
            Ob[(size_t)(b_*SS + qg)*DD + h*HDIM + f*16 + l16] = f2bf(ov[rg]);
        }
    }
}

// ---------------- launch ----------------
extern "C" void kernel_launch(void* const* d_in, const int* in_sizes, int n_in,
                              void* d_out, int out_size, void* d_ws, size_t ws_size,
                              hipStream_t stream)
{
    const float* xs[3] = { (const float*)d_in[0], (const float*)d_in[1], (const float*)d_in[2] };
    const float* Vw[4] = { (const float*)d_in[3], (const float*)d_in[6], (const float*)d_in[9],  (const float*)d_in[12] };
    const float* Uw[4] = { (const float*)d_in[4], (const float*)d_in[7], (const float*)d_in[10], (const float*)d_in[13] };
    const float* bw[4] = { (const float*)d_in[5], (const float*)d_in[8], (const float*)d_in[11], (const float*)d_in[14] };

    char* ws = (char*)d_ws;
    size_t off = 0;
    auto alloc = [&](size_t bytes) -> char* {
        char* p = ws + off;
        off += (bytes + 255) & ~(size_t)255;
        return p;
    };
    u16* wV[4]; for (int i = 0; i < 4; ++i) wV[i] = (u16*)alloc((size_t)RK*DD*2);
    u16* wU[4]; for (int i = 0; i < 4; ++i) wU[i] = (u16*)alloc((size_t)DD*RKP*2);
    u16* Tb[3]; for (int i = 0; i < 3; ++i) Tb[i] = (u16*)alloc((size_t)BB*SS*RKP*2);
    u16* hb[2]; for (int i = 0; i < 2; ++i) hb[i] = (u16*)alloc((size_t)BB*SS*DD*2);
    u16* vTb = (u16*)alloc((size_t)BB*SS*DD*2);
    u16* Ob  = (u16*)alloc((size_t)BB*SS*DD*2);
    (void)ws_size; (void)in_sizes; (void)n_in; (void)out_size;

    // weight conversions (batched over the 4 weights via blockIdx.y)
    {
        C4 cv = { Vw[0], Vw[1], Vw[2], Vw[3], wV[0], wV[1], wV[2], wV[3] };
        cvt_bf16_b4<<<dim3((RK*DD/4 + 255)/256, 4), 256, 0, stream>>>(cv, RK*DD/4);
        C4 cu = { Uw[0], Uw[1], Uw[2], Uw[3], wU[0], wU[1], wU[2], wU[3] };
        cvt_pad_b4<<<dim3((DD*RKP + 255)/256, 4), 256, 0, stream>>>(cu, DD*RKP);
    }

    const int MROWS = BB*SS;           // 4096
    // stage 1 (q,k,v batched over z): X @ V^T -> T[4096x256 padded]
    {
        B3 g = { xs[0], xs[1], xs[2], wV[0], wV[1], wV[2],
                 nullptr, nullptr, nullptr, Tb[0], Tb[1], Tb[2] };
        gemm_nt_k<1,0,0,0,0><<<dim3(MROWS/64, RKP/64, 3), 256, 0, stream>>>(
            g, DD, DD, RK, RKP, DD);
    }
    // stage 2 (batched): T @ U^T + b -> qh (scaled 1/8), kh, vT (transposed epilogue)
    {
        B3 g = { Tb[0], Tb[1], Tb[2], wU[0], wU[1], wU[2],
                 bw[0], bw[1], bw[2], hb[0], hb[1], vTb };
        gemm_nt_k<0,0,1,1,1><<<dim3(MROWS/64, DD/64, 3), 256, 0, stream>>>(
            g, RKP, RKP, DD, DD, RKP);
    }

    float* attn_out = (float*)d_out + (size_t)BB*SS*DD;
    attn_k<<<BH*32, 256, 0, stream>>>(hb[0], hb[1], vTb, attn_out, Ob);

    // output projection: O @ Vo^T -> T; T @ Uo^T + bo -> d_out (fp32)
    {
        B3 g = { Ob, Ob, Ob, wV[3], wV[3], wV[3],
                 nullptr, nullptr, nullptr, Tb[0], Tb[0], Tb[0] };
        gemm_nt_k<0,0,0,0,0><<<dim3(MROWS/64, RKP/64, 1), 256, 0, stream>>>(
            g, DD, DD, RK, RKP, DD);
    }
    {
        B3 g = { Tb[0], Tb[0], Tb[0], wU[3], wU[3], wU[3],
                 bw[3], bw[3], bw[3], d_out, d_out, d_out };
        gemm_nt_k<0,1,1,0,0><<<dim3(MROWS/64, DD/64, 1), 256, 0, stream>>>(
            g, RKP, RKP, DD, DD, RKP);
    }
}

// Round 6
// 747.456 us; speedup vs baseline: 1.5637x; 1.0100x over previous
//
#include <hip/hip_runtime.h>
#include <stdint.h>

#define BB   2
#define SS   2048
#define DD   1024
#define NH   16
#define RK   204
#define RKP  256
#define HDIM 64
#define BH   (BB*NH)

typedef __attribute__((ext_vector_type(8))) short short8;
typedef __attribute__((ext_vector_type(4))) float f32x4;
typedef unsigned short u16;
typedef unsigned int   u32;

#define LOG2E  1.4426950408889634f

static __device__ __forceinline__ u32 cvtpk(float lo, float hi) {
    u32 r; asm("v_cvt_pk_bf16_f32 %0, %1, %2" : "=v"(r) : "v"(lo), "v"(hi)); return r;
}
static __device__ __forceinline__ u16 f2bf(float f) { return (u16)cvtpk(f, f); }
static __device__ __forceinline__ u32 pack2(float lo, float hi) { return cvtpk(lo, hi); }
static __device__ __forceinline__ float exp2_hw(float x) {
    float r; asm("v_exp_f32 %0, %1" : "=v"(r) : "v"(x)); return r;
}

// ---------------- batched conversion kernels ----------------
struct C4 { const float *s0, *s1, *s2, *s3; u16 *d0, *d1, *d2, *d3; };

__global__ void cvt_bf16_b4(C4 c, int n4) {
    int y = blockIdx.y;
    const float* in = (y==0)?c.s0:(y==1)?c.s1:(y==2)?c.s2:c.s3;
    u16* out = (y==0)?c.d0:(y==1)?c.d1:(y==2)?c.d2:c.d3;
    int i = blockIdx.x * blockDim.x + threadIdx.x;
    if (i < n4) {
        float4 f = ((const float4*)in)[i];
        ((uint2*)out)[i] = make_uint2(pack2(f.x, f.y), pack2(f.z, f.w));
    }
}

// U (DD x RK) fp32 -> (DD x RKP) bf16, zero pad cols [RK,RKP)
__global__ void cvt_pad_b4(C4 c, int n) {
    int y = blockIdx.y;
    const float* in = (y==0)?c.s0:(y==1)?c.s1:(y==2)?c.s2:c.s3;
    u16* out = (y==0)?c.d0:(y==1)?c.d1:(y==2)?c.d2:c.d3;
    int i = blockIdx.x * blockDim.x + threadIdx.x;
    if (i >= n) return;
    int row = i >> 8, col = i & (RKP - 1);
    out[i] = (col < RK) ? f2bf(in[row * RK + col]) : (u16)0;
}

// ---------------- z-batched NT GEMM, BK=128: C[M x N] = A[M x K] * B[N x K]^T (+bias) ----
// VT_LAST: z==2 writes vT[bh][hd][s] via LDS transpose. QSC: z==0 output scaled by 0.125.
struct B3 {
    const void *A0, *A1, *A2;
    const u16  *B0, *B1, *B2;
    const float *bb0, *bb1, *bb2;
    void *C0, *C1, *C2;
};

#define LDW 136   // 128 + 8 u16 pad: row stride 272B -> 2-way bank alias only (free)

template<int A_F32, int OUT_F32, int HAS_BIAS, int VT_LAST, int QSC>
__global__ __launch_bounds__(256)
void gemm_nt_k(B3 g, int lda, int ldb, int nrowsB, int ldc, int K)
{
    const int z = blockIdx.z;
    const void* Ap  = (z==0)?g.A0:(z==1)?g.A1:g.A2;
    const u16*  Bp  = (z==0)?g.B0:(z==1)?g.B1:g.B2;
    const float* bias = (z==0)?g.bb0:(z==1)?g.bb1:g.bb2;
    void* Cp = (z==0)?g.C0:(z==1)?g.C1:g.C2;

    __shared__ __align__(16) u16 As[64*LDW];
    __shared__ __align__(16) u16 Bs[64*LDW];
    const int row0 = blockIdx.x * 64;
    const int col0 = blockIdx.y * 64;
    const int t = threadIdx.x;
    const int w = t >> 6, lane = t & 63, quad = lane >> 4, l16 = lane & 15;
    const int r = t >> 2, seg = t & 3;          // r: row 0..63, seg: 32-u16 chunk 0..3

    f32x4 acc0 = 0.f, acc1 = 0.f, acc2 = 0.f, acc3 = 0.f;

    for (int k0 = 0; k0 < K; k0 += 128) {
        __syncthreads();
        if (A_F32) {
            const float* ga = (const float*)Ap + (size_t)(row0 + r) * lda + k0 + seg*32;
            float4 f0 = ((const float4*)ga)[0];
            float4 f1 = ((const float4*)ga)[1];
            float4 f2 = ((const float4*)ga)[2];
            float4 f3 = ((const float4*)ga)[3];
            float4 f4 = ((const float4*)ga)[4];
            float4 f5 = ((const float4*)ga)[5];
            float4 f6 = ((const float4*)ga)[6];
            float4 f7 = ((const float4*)ga)[7];
            uint4 s0 = { pack2(f0.x,f0.y), pack2(f0.z,f0.w), pack2(f1.x,f1.y), pack2(f1.z,f1.w) };
            uint4 s1 = { pack2(f2.x,f2.y), pack2(f2.z,f2.w), pack2(f3.x,f3.y), pack2(f3.z,f3.w) };
            uint4 s2 = { pack2(f4.x,f4.y), pack2(f4.z,f4.w), pack2(f5.x,f5.y), pack2(f5.z,f5.w) };
            uint4 s3 = { pack2(f6.x,f6.y), pack2(f6.z,f6.w), pack2(f7.x,f7.y), pack2(f7.z,f7.w) };
            *(uint4*)(As + r*LDW + seg*32)      = s0;
            *(uint4*)(As + r*LDW + seg*32 + 8)  = s1;
            *(uint4*)(As + r*LDW + seg*32 + 16) = s2;
            *(uint4*)(As + r*LDW + seg*32 + 24) = s3;
        } else {
            const u16* ga = (const u16*)Ap + (size_t)(row0 + r) * lda + k0 + seg*32;
            *(uint4*)(As + r*LDW + seg*32)      = ((const uint4*)ga)[0];
            *(uint4*)(As + r*LDW + seg*32 + 8)  = ((const uint4*)ga)[1];
            *(uint4*)(As + r*LDW + seg*32 + 16) = ((const uint4*)ga)[2];
            *(uint4*)(As + r*LDW + seg*32 + 24) = ((const uint4*)ga)[3];
        }
        {
            uint4 b0 = {0,0,0,0}, b1 = {0,0,0,0}, b2 = {0,0,0,0}, b3 = {0,0,0,0};
            if (col0 + r < nrowsB) {
                const u16* gb = Bp + (size_t)(col0 + r) * ldb + k0 + seg*32;
                b0 = ((const uint4*)gb)[0];
                b1 = ((const uint4*)gb)[1];
                b2 = ((const uint4*)gb)[2];
                b3 = ((const uint4*)gb)[3];
            }
            *(uint4*)(Bs + r*LDW + seg*32)      = b0;
            *(uint4*)(Bs + r*LDW + seg*32 + 8)  = b1;
            *(uint4*)(Bs + r*LDW + seg*32 + 16) = b2;
            *(uint4*)(Bs + r*LDW + seg*32 + 24) = b3;
        }
        __syncthreads();
        #pragma unroll
        for (int c = 0; c < 4; ++c) {
            short8 a = *(const short8*)(As + (w*16 + l16)*LDW + c*32 + quad*8);
            short8 b0v = *(const short8*)(Bs + (0*16 + l16)*LDW + c*32 + quad*8);
            acc0 = __builtin_amdgcn_mfma_f32_16x16x32_bf16(a, b0v, acc0, 0, 0, 0);
            short8 b1v = *(const short8*)(Bs + (1*16 + l16)*LDW + c*32 + quad*8);
            acc1 = __builtin_amdgcn_mfma_f32_16x16x32_bf16(a, b1v, acc1, 0, 0, 0);
            short8 b2v = *(const short8*)(Bs + (2*16 + l16)*LDW + c*32 + quad*8);
            acc2 = __builtin_amdgcn_mfma_f32_16x16x32_bf16(a, b2v, acc2, 0, 0, 0);
            short8 b3v = *(const short8*)(Bs + (3*16 + l16)*LDW + c*32 + quad*8);
            acc3 = __builtin_amdgcn_mfma_f32_16x16x32_bf16(a, b3v, acc3, 0, 0, 0);
        }
    }

    if (VT_LAST && z == 2) {
        // write V-head transpose directly: vT[(bh*HDIM + hd)*SS + s]
        __syncthreads();   // all waves done reading As/Bs
        #pragma unroll
        for (int f = 0; f < 4; ++f) {
            f32x4 a = (f==0) ? acc0 : (f==1) ? acc1 : (f==2) ? acc2 : acc3;
            int col = f*16 + l16;           // hd within head
            float bv = HAS_BIAS ? bias[col0 + col] : 0.f;
            #pragma unroll
            for (int rg = 0; rg < 4; ++rg) {
                int rowl = w*16 + quad*4 + rg;   // s within tile
                As[col*72 + rowl] = f2bf(a[rg] + bv);   // As reused as [hd][s] (72-stride)
            }
        }
        __syncthreads();
        const int b_ = row0 >> 11;
        const int s0 = row0 & (SS - 1);
        const int h  = col0 >> 6;
        u16* dst = (u16*)Cp + ((size_t)((b_*NH + h)*HDIM + r))*SS + s0 + seg*16;
        ((uint4*)dst)[0] = *(const uint4*)(As + r*72 + seg*16);
        ((uint4*)dst)[1] = *(const uint4*)(As + r*72 + seg*16 + 8);
        return;
    }

    const float osc = (QSC && z == 0) ? 0.125f : 1.f;
    #pragma unroll
    for (int f = 0; f < 4; ++f) {
        f32x4 a = (f==0) ? acc0 : (f==1) ? acc1 : (f==2) ? acc2 : acc3;
        int col = col0 + f*16 + l16;
        float bv = HAS_BIAS ? bias[col] : 0.f;
        #pragma unroll
        for (int rg = 0; rg < 4; ++rg) {
            int rowg = row0 + w*16 + quad*4 + rg;
            float val = (a[rg] + bv) * osc;
            if (col >= nrowsB) val = 0.f;
            if (OUT_F32) ((float*)Cp)[(size_t)rowg*ldc + col] = val;
            else         ((u16*)Cp)[(size_t)rowg*ldc + col]  = f2bf(val);
        }
    }
}

// ---------------- fused attention (no-max softmax: scores bounded ~16 << 88) ----------------
#define QKT_8(BUF,sa0,sa1,sa2,sa3) do { \
    short8 b0 = *(const short8*)(BUF + (0*16 + l16)*72 + quad*8); \
    sa0 = __builtin_amdgcn_mfma_f32_16x16x32_bf16(q0, b0, sa0, 0,0,0); \
    short8 b0b = *(const short8*)(BUF + (0*16 + l16)*72 + 32 + quad*8); \
    sa0 = __builtin_amdgcn_mfma_f32_16x16x32_bf16(q1, b0b, sa0, 0,0,0); \
    short8 b1 = *(const short8*)(BUF + (1*16 + l16)*72 + quad*8); \
    sa1 = __builtin_amdgcn_mfma_f32_16x16x32_bf16(q0, b1, sa1, 0,0,0); \
    short8 b1b = *(const short8*)(BUF + (1*16 + l16)*72 + 32 + quad*8); \
    sa1 = __builtin_amdgcn_mfma_f32_16x16x32_bf16(q1, b1b, sa1, 0,0,0); \
    short8 b2 = *(const short8*)(BUF + (2*16 + l16)*72 + quad*8); \
    sa2 = __builtin_amdgcn_mfma_f32_16x16x32_bf16(q0, b2, sa2, 0,0,0); \
    short8 b2b = *(const short8*)(BUF + (2*16 + l16)*72 + 32 + quad*8); \
    sa2 = __builtin_amdgcn_mfma_f32_16x16x32_bf16(q1, b2b, sa2, 0,0,0); \
    short8 b3 = *(const short8*)(BUF + (3*16 + l16)*72 + quad*8); \
    sa3 = __builtin_amdgcn_mfma_f32_16x16x32_bf16(q0, b3, sa3, 0,0,0); \
    short8 b3b = *(const short8*)(BUF + (3*16 + l16)*72 + 32 + quad*8); \
    sa3 = __builtin_amdgcn_mfma_f32_16x16x32_bf16(q1, b3b, sa3, 0,0,0); \
} while (0)

// phase-1 sum update, interior tile (no masking)
static __device__ __forceinline__ void p1_int(
    const f32x4& sa0, const f32x4& sa1, const f32x4& sa2, const f32x4& sa3, float* l)
{
    #pragma unroll
    for (int rg = 0; rg < 4; ++rg) {
        l[rg] += (exp2_hw(sa0[rg]*LOG2E) + exp2_hw(sa1[rg]*LOG2E))
               + (exp2_hw(sa2[rg]*LOG2E) + exp2_hw(sa3[rg]*LOG2E));
    }
}
// phase-1 sum update, diagonal tile (causal masking)
static __device__ __forceinline__ void p1_diag(
    const f32x4& sa0, const f32x4& sa1, const f32x4& sa2, const f32x4& sa3,
    float* l, int key0, int qg0)
{
    #pragma unroll
    for (int rg = 0; rg < 4; ++rg) {
        int qg = qg0 + rg;
        float e0 = (key0      <= qg) ? exp2_hw(sa0[rg]*LOG2E) : 0.f;
        float e1 = (key0 + 16 <= qg) ? exp2_hw(sa1[rg]*LOG2E) : 0.f;
        float e2 = (key0 + 32 <= qg) ? exp2_hw(sa2[rg]*LOG2E) : 0.f;
        float e3 = (key0 + 48 <= qg) ? exp2_hw(sa3[rg]*LOG2E) : 0.f;
        l[rg] += (e0+e1) + (e2+e3);
    }
}

__global__ __launch_bounds__(256)
void attn_k(const u16* __restrict__ qh, const u16* __restrict__ kh,
            const u16* __restrict__ vT,
            float* __restrict__ attn_out, u16* __restrict__ Ob)
{
    __shared__ __align__(16) u16 Ks[64*72];
    __shared__ __align__(16) u16 Vs[64*72];
    __shared__ __align__(16) u16 Ps[64*72];
    const int blk = blockIdx.x;          // bh*32 + qt
    const int qt = blk & 31, bh = blk >> 5;
    const int b_ = bh >> 4, h = bh & (NH - 1);
    const int qbase = qt * 64;
    const int t = threadIdx.x, w = t >> 6, lane = t & 63, quad = lane >> 4, l16 = lane & 15;
    const int r = t >> 2, seg = t & 3;

    // q is pre-scaled by 1/8 at the projection epilogue (exact power-of-2)
    const u16* qrow = qh + (size_t)(b_*SS + qbase + w*16 + l16)*DD + h*HDIM;
    short8 q0 = *(const short8*)(qrow + quad*8);
    short8 q1 = *(const short8*)(qrow + 32 + quad*8);

    const u16* kstage = kh + (size_t)(b_*SS + r)*DD + h*HDIM + seg*16;
    const u16* vstage = vT + ((size_t)(bh*HDIM + r))*SS + seg*16;
    const int qg0 = qbase + w*16 + quad*4;

    // ---------------- phase 1: per-lane sum l, double-tile staged ----------------
    float l[4] = {0.f, 0.f, 0.f, 0.f};

    for (int kt0 = 0; kt0 <= qt; kt0 += 2) {
        const bool two = (kt0 + 1) <= qt;
        __syncthreads();
        {
            const u16* krow = kstage + (size_t)kt0*64*DD;
            *(uint4*)(Ks + r*72 + seg*16)     = ((const uint4*)krow)[0];
            *(uint4*)(Ks + r*72 + seg*16 + 8) = ((const uint4*)krow)[1];
            if (two) {
                const u16* krow2 = krow + (size_t)64*DD;
                *(uint4*)(Vs + r*72 + seg*16)     = ((const uint4*)krow2)[0];
                *(uint4*)(Vs + r*72 + seg*16 + 8) = ((const uint4*)krow2)[1];
            }
        }
        __syncthreads();
        {
            f32x4 sa0 = 0.f, sa1 = 0.f, sa2 = 0.f, sa3 = 0.f;
            QKT_8(Ks, sa0, sa1, sa2, sa3);
            if (kt0 < qt) p1_int(sa0, sa1, sa2, sa3, l);
            else          p1_diag(sa0, sa1, sa2, sa3, l, kt0*64 + l16, qg0);
        }
        if (two) {
            f32x4 sa0 = 0.f, sa1 = 0.f, sa2 = 0.f, sa3 = 0.f;
            QKT_8(Vs, sa0, sa1, sa2, sa3);
            if (kt0 + 1 < qt) p1_int(sa0, sa1, sa2, sa3, l);
            else              p1_diag(sa0, sa1, sa2, sa3, l, (kt0+1)*64 + l16, qg0);
        }
    }

    // 16-lane sum merge; then fold 1/l into the exponent: lg2rl = -log2(l)
    float lg2rl[4];
    #pragma unroll
    for (int rg = 0; rg < 4; ++rg) {
        #pragma unroll
        for (int d = 1; d < 16; d <<= 1) l[rg] += __shfl_xor(l[rg], d);
        lg2rl[rg] = -__log2f(l[rg]);
    }

    // ---------------- phase 2: P write + O = P*V ----------------
    f32x4 oa0 = 0.f, oa1 = 0.f, oa2 = 0.f, oa3 = 0.f;
    float* attn_base = attn_out + (size_t)bh * SS * SS;
    float* rp0 = attn_base + (size_t)(qg0 + 0)*SS + l16;
    float* rp1 = attn_base + (size_t)(qg0 + 1)*SS + l16;
    float* rp2 = attn_base + (size_t)(qg0 + 2)*SS + l16;
    float* rp3 = attn_base + (size_t)(qg0 + 3)*SS + l16;
    const int psrow = w*16 + quad*4;

    for (int kt = 0; kt <= qt; ++kt) {
        __syncthreads();
        {
            const u16* krow = kstage + (size_t)kt*64*DD;
            *(uint4*)(Ks + r*72 + seg*16)     = ((const uint4*)krow)[0];
            *(uint4*)(Ks + r*72 + seg*16 + 8) = ((const uint4*)krow)[1];
            const u16* vrow = vstage + kt*64;
            *(uint4*)(Vs + r*72 + seg*16)     = ((const uint4*)vrow)[0];
            *(uint4*)(Vs + r*72 + seg*16 + 8) = ((const uint4*)vrow)[1];
        }
        __syncthreads();

        f32x4 sa0 = 0.f, sa1 = 0.f, sa2 = 0.f, sa3 = 0.f;
        QKT_8(Ks, sa0, sa1, sa2, sa3);

        if (kt < qt) {
            #pragma unroll
            for (int f = 0; f < 4; ++f) {
                f32x4 sv = (f==0) ? sa0 : (f==1) ? sa1 : (f==2) ? sa2 : sa3;
                float p0 = exp2_hw(__builtin_fmaf(sv[0], LOG2E, lg2rl[0]));
                float p1 = exp2_hw(__builtin_fmaf(sv[1], LOG2E, lg2rl[1]));
                float p2 = exp2_hw(__builtin_fmaf(sv[2], LOG2E, lg2rl[2]));
                float p3 = exp2_hw(__builtin_fmaf(sv[3], LOG2E, lg2rl[3]));
                rp0[f*16] = p0; rp1[f*16] = p1; rp2[f*16] = p2; rp3[f*16] = p3;
                u32 pk01 = cvtpk(p0, p1), pk23 = cvtpk(p2, p3);
                Ps[(psrow+0)*72 + f*16 + l16] = (u16)pk01;
                Ps[(psrow+1)*72 + f*16 + l16] = (u16)(pk01 >> 16);
                Ps[(psrow+2)*72 + f*16 + l16] = (u16)pk23;
                Ps[(psrow+3)*72 + f*16 + l16] = (u16)(pk23 >> 16);
            }
        } else {
            int kbase = kt*64;
            #pragma unroll
            for (int f = 0; f < 4; ++f) {
                f32x4 sv = (f==0) ? sa0 : (f==1) ? sa1 : (f==2) ? sa2 : sa3;
                int key = kbase + f*16 + l16;
                float p0 = (key <= qg0+0) ? exp2_hw(__builtin_fmaf(sv[0], LOG2E, lg2rl[0])) : 0.f;
                float p1 = (key <= qg0+1) ? exp2_hw(__builtin_fmaf(sv[1], LOG2E, lg2rl[1])) : 0.f;
                float p2 = (key <= qg0+2) ? exp2_hw(__builtin_fmaf(sv[2], LOG2E, lg2rl[2])) : 0.f;
                float p3 = (key <= qg0+3) ? exp2_hw(__builtin_fmaf(sv[3], LOG2E, lg2rl[3])) : 0.f;
                rp0[f*16] = p0; rp1[f*16] = p1; rp2[f*16] = p2; rp3[f*16] = p3;
                u32 pk01 = cvtpk(p0, p1), pk23 = cvtpk(p2, p3);
                Ps[(psrow+0)*72 + f*16 + l16] = (u16)pk01;
                Ps[(psrow+1)*72 + f*16 + l16] = (u16)(pk01 >> 16);
                Ps[(psrow+2)*72 + f*16 + l16] = (u16)pk23;
                Ps[(psrow+3)*72 + f*16 + l16] = (u16)(pk23 >> 16);
            }
        }
        rp0 += 64; rp1 += 64; rp2 += 64; rp3 += 64;

        // Ps rows are wave-private (wave w writes and reads rows w*16..w*16+15);
        // per-wave LDS pipe is in-order — compiler-level fence only, no barrier.
        asm volatile("" ::: "memory");

        // O += P * V
        #pragma unroll
        for (int c = 0; c < 2; ++c) {
            short8 pa = *(const short8*)(Ps + (w*16 + l16)*72 + c*32 + quad*8);
            short8 v0 = *(const short8*)(Vs + (0*16 + l16)*72 + c*32 + quad*8);
            oa0 = __builtin_amdgcn_mfma_f32_16x16x32_bf16(pa, v0, oa0, 0,0,0);
            short8 v1 = *(const short8*)(Vs + (1*16 + l16)*72 + c*32 + quad*8);
            oa1 = __builtin_amdgcn_mfma_f32_16x16x32_bf16(pa, v1, oa1, 0,0,0);
            short8 v2 = *(const short8*)(Vs + (2*16 + l16)*72 + c*32 + quad*8);
            oa2 = __builtin_amdgcn_mfma_f32_16x16x32_bf16(pa, v2, oa2, 0,0,0);
            short8 v3 = *(const short8*)(Vs + (3*16 + l16)*72 + c*32 + quad*8);
            oa3 = __builtin_amdgcn_mfma_f32_16x16x32_bf16(pa, v3, oa3, 0,0,0);
        }
    }

    // fully-masked upper tiles: explicit zeros (d_out is poisoned)
    for (int kt = qt + 1; kt < 32; ++kt) {
        int kbase = kt * 64;
        f32x4 z = 0.f;
        f32x4* p = (f32x4*)(attn_base + (size_t)(qbase + r)*SS + kbase + seg*16);
        p[0] = z; p[1] = z; p[2] = z; p[3] = z;
    }

    #pragma unroll
    for (int f = 0; f < 4; ++f) {
        f32x4 ov = (f==0) ? oa0 : (f==1) ? oa1 : (f==2) ? oa2 : oa3;
        #pragma unroll
        for (int rg = 0; rg < 4; ++rg) {
            int qg = qg0 + rg;
            Ob[(size_t)(b_*SS + qg)*DD + h*HDIM + f*16 + l16] = f2bf(ov[rg]);
        }
    }
}

// ---------------- launch ----------------
extern "C" void kernel_launch(void* const* d_in, const int* in_sizes, int n_in,
                              void* d_out, int out_size, void* d_ws, size_t ws_size,
                              hipStream_t stream)
{
    const float* xs[3] = { (const float*)d_in[0], (const float*)d_in[1], (const float*)d_in[2] };
    const float* Vw[4] = { (const float*)d_in[3], (const float*)d_in[6], (const float*)d_in[9],  (const float*)d_in[12] };
    const float* Uw[4] = { (const float*)d_in[4], (const float*)d_in[7], (const float*)d_in[10], (const float*)d_in[13] };
    const float* bw[4] = { (const float*)d_in[5], (const float*)d_in[8], (const float*)d_in[11], (const float*)d_in[14] };

    char* ws = (char*)d_ws;
    size_t off = 0;
    auto alloc = [&](size_t bytes) -> char* {
        char* p = ws + off;
        off += (bytes + 255) & ~(size_t)255;
        return p;
    };
    u16* wV[4]; for (int i = 0; i < 4; ++i) wV[i] = (u16*)alloc((size_t)RK*DD*2);
    u16* wU[4]; for (int i = 0; i < 4; ++i) wU[i] = (u16*)alloc((size_t)DD*RKP*2);
    u16* Tb[3]; for (int i = 0; i < 3; ++i) Tb[i] = (u16*)alloc((size_t)BB*SS*RKP*2);
    u16* hb[2]; for (int i = 0; i < 2; ++i) hb[i] = (u16*)alloc((size_t)BB*SS*DD*2);
    u16* vTb = (u16*)alloc((size_t)BB*SS*DD*2);
    u16* Ob  = (u16*)alloc((size_t)BB*SS*DD*2);
    (void)ws_size; (void)in_sizes; (void)n_in; (void)out_size;

    // weight conversions (batched over the 4 weights via blockIdx.y)
    {
        C4 cv = { Vw[0], Vw[1], Vw[2], Vw[3], wV[0], wV[1], wV[2], wV[3] };
        cvt_bf16_b4<<<dim3((RK*DD/4 + 255)/256, 4), 256, 0, stream>>>(cv, RK*DD/4);
        C4 cu = { Uw[0], Uw[1], Uw[2], Uw[3], wU[0], wU[1], wU[2], wU[3] };
        cvt_pad_b4<<<dim3((DD*RKP + 255)/256, 4), 256, 0, stream>>>(cu, DD*RKP);
    }

    const int MROWS = BB*SS;           // 4096
    // stage 1 (q,k,v batched over z): X @ V^T -> T[4096x256 padded]
    {
        B3 g = { xs[0], xs[1], xs[2], wV[0], wV[1], wV[2],
                 nullptr, nullptr, nullptr, Tb[0], Tb[1], Tb[2] };
        gemm_nt_k<1,0,0,0,0><<<dim3(MROWS/64, RKP/64, 3), 256, 0, stream>>>(
            g, DD, DD, RK, RKP, DD);
    }
    // stage 2 (batched): T @ U^T + b -> qh (scaled 1/8), kh, vT (transposed epilogue)
    {
        B3 g = { Tb[0], Tb[1], Tb[2], wU[0], wU[1], wU[2],
                 bw[0], bw[1], bw[2], hb[0], hb[1], vTb };
        gemm_nt_k<0,0,1,1,1><<<dim3(MROWS/64, DD/64, 3), 256, 0, stream>>>(
            g, RKP, RKP, DD, DD, RKP);
    }

    float* attn_out = (float*)d_out + (size_t)BB*SS*DD;
    attn_k<<<BH*32, 256, 0, stream>>>(hb[0], hb[1], vTb, attn_out, Ob);

    // output projection: O @ Vo^T -> T; T @ Uo^T + bo -> d_out (fp32)
    {
        B3 g = { Ob, Ob, Ob, wV[3], wV[3], wV[3],
                 nullptr, nullptr, nullptr, Tb[0], Tb[0], Tb[0] };
        gemm_nt_k<0,0,0,0,0><<<dim3(MROWS/64, RKP/64, 1), 256, 0, stream>>>(
            g, DD, DD, RK, RKP, DD);
    }
    {
        B3 g = { Tb[0], Tb[0], Tb[0], wU[3], wU[3], wU[3],
                 bw[3], bw[3], bw[3], d_out, d_out, d_out };
        gemm_nt_k<0,1,1,0,0><<<dim3(MROWS/64, DD/64, 1), 256, 0, stream>>>(
            g, RKP, RKP, DD, DD, RKP);
    }
}

// Round 7
// 737.268 us; speedup vs baseline: 1.5853x; 1.0138x over previous
//
#include <hip/hip_runtime.h>
#include <stdint.h>

#define BB   2
#define SS   2048
#define DD   1024
#define NH   16
#define RK   204
#define RKP  256
#define HDIM 64
#define BH   (BB*NH)

typedef __attribute__((ext_vector_type(8))) short short8;
typedef __attribute__((ext_vector_type(4))) float f32x4;
typedef unsigned short u16;
typedef unsigned int   u32;

#define LOG2E  1.4426950408889634f

static __device__ __forceinline__ u32 cvtpk(float lo, float hi) {
    u32 r; asm("v_cvt_pk_bf16_f32 %0, %1, %2" : "=v"(r) : "v"(lo), "v"(hi)); return r;
}
static __device__ __forceinline__ u16 f2bf(float f) { return (u16)cvtpk(f, f); }
static __device__ __forceinline__ u32 pack2(float lo, float hi) { return cvtpk(lo, hi); }
static __device__ __forceinline__ float exp2_hw(float x) {
    float r; asm("v_exp_f32 %0, %1" : "=v"(r) : "v"(x)); return r;
}

// ---------------- combined conversion kernel (one launch) ----------------
// y<4: V weights fp32->bf16 straight; y>=4: U weights fp32 -> padded [DD x RKP] bf16
struct C8 { const float* s[8]; u16* d[8]; };

__global__ void cvt_all_k(C8 c) {
    int y = blockIdx.y;
    int i = blockIdx.x * blockDim.x + threadIdx.x;
    if (y < 4) {
        if (i < RK*DD/4) {
            float4 f = ((const float4*)c.s[y])[i];
            ((uint2*)c.d[y])[i] = make_uint2(pack2(f.x, f.y), pack2(f.z, f.w));
        }
    } else {
        if (i < DD*RKP) {
            int row = i >> 8, col = i & (RKP - 1);
            c.d[y][i] = (col < RK) ? f2bf(c.s[y][row * RK + col]) : (u16)0;
        }
    }
}

// ---------------- z-batched NT GEMM, BK=128: C[M x N] = A[M x K] * B[N x K]^T (+bias) ----
// VT_LAST: z==2 writes vT[bh][hd][s] via LDS transpose. QSC: z==0 output scaled by 0.125.
struct B3 {
    const void *A0, *A1, *A2;
    const u16  *B0, *B1, *B2;
    const float *bb0, *bb1, *bb2;
    void *C0, *C1, *C2;
};

#define LDW 136   // 128 + 8 u16 pad: row stride 272B -> 2-way bank alias only (free)

template<int A_F32, int OUT_F32, int HAS_BIAS, int VT_LAST, int QSC>
__global__ __launch_bounds__(256)
void gemm_nt_k(B3 g, int lda, int ldb, int nrowsB, int ldc, int K)
{
    const int z = blockIdx.z;
    const void* Ap  = (z==0)?g.A0:(z==1)?g.A1:g.A2;
    const u16*  Bp  = (z==0)?g.B0:(z==1)?g.B1:g.B2;
    const float* bias = (z==0)?g.bb0:(z==1)?g.bb1:g.bb2;
    void* Cp = (z==0)?g.C0:(z==1)?g.C1:g.C2;

    __shared__ __align__(16) u16 As[64*LDW];
    __shared__ __align__(16) u16 Bs[64*LDW];
    const int row0 = blockIdx.x * 64;
    const int col0 = blockIdx.y * 64;
    const int t = threadIdx.x;
    const int w = t >> 6, lane = t & 63, quad = lane >> 4, l16 = lane & 15;
    const int r = t >> 2, seg = t & 3;          // r: row 0..63, seg: 32-u16 chunk 0..3

    f32x4 acc0 = 0.f, acc1 = 0.f, acc2 = 0.f, acc3 = 0.f;

    for (int k0 = 0; k0 < K; k0 += 128) {
        __syncthreads();
        if (A_F32) {
            const float* ga = (const float*)Ap + (size_t)(row0 + r) * lda + k0 + seg*32;
            float4 f0 = ((const float4*)ga)[0];
            float4 f1 = ((const float4*)ga)[1];
            float4 f2 = ((const float4*)ga)[2];
            float4 f3 = ((const float4*)ga)[3];
            float4 f4 = ((const float4*)ga)[4];
            float4 f5 = ((const float4*)ga)[5];
            float4 f6 = ((const float4*)ga)[6];
            float4 f7 = ((const float4*)ga)[7];
            uint4 s0 = { pack2(f0.x,f0.y), pack2(f0.z,f0.w), pack2(f1.x,f1.y), pack2(f1.z,f1.w) };
            uint4 s1 = { pack2(f2.x,f2.y), pack2(f2.z,f2.w), pack2(f3.x,f3.y), pack2(f3.z,f3.w) };
            uint4 s2 = { pack2(f4.x,f4.y), pack2(f4.z,f4.w), pack2(f5.x,f5.y), pack2(f5.z,f5.w) };
            uint4 s3 = { pack2(f6.x,f6.y), pack2(f6.z,f6.w), pack2(f7.x,f7.y), pack2(f7.z,f7.w) };
            *(uint4*)(As + r*LDW + seg*32)      = s0;
            *(uint4*)(As + r*LDW + seg*32 + 8)  = s1;
            *(uint4*)(As + r*LDW + seg*32 + 16) = s2;
            *(uint4*)(As + r*LDW + seg*32 + 24) = s3;
        } else {
            const u16* ga = (const u16*)Ap + (size_t)(row0 + r) * lda + k0 + seg*32;
            *(uint4*)(As + r*LDW + seg*32)      = ((const uint4*)ga)[0];
            *(uint4*)(As + r*LDW + seg*32 + 8)  = ((const uint4*)ga)[1];
            *(uint4*)(As + r*LDW + seg*32 + 16) = ((const uint4*)ga)[2];
            *(uint4*)(As + r*LDW + seg*32 + 24) = ((const uint4*)ga)[3];
        }
        {
            uint4 b0 = {0,0,0,0}, b1 = {0,0,0,0}, b2 = {0,0,0,0}, b3 = {0,0,0,0};
            if (col0 + r < nrowsB) {
                const u16* gb = Bp + (size_t)(col0 + r) * ldb + k0 + seg*32;
                b0 = ((const uint4*)gb)[0];
                b1 = ((const uint4*)gb)[1];
                b2 = ((const uint4*)gb)[2];
                b3 = ((const uint4*)gb)[3];
            }
            *(uint4*)(Bs + r*LDW + seg*32)      = b0;
            *(uint4*)(Bs + r*LDW + seg*32 + 8)  = b1;
            *(uint4*)(Bs + r*LDW + seg*32 + 16) = b2;
            *(uint4*)(Bs + r*LDW + seg*32 + 24) = b3;
        }
        __syncthreads();
        #pragma unroll
        for (int c = 0; c < 4; ++c) {
            short8 a = *(const short8*)(As + (w*16 + l16)*LDW + c*32 + quad*8);
            short8 b0v = *(const short8*)(Bs + (0*16 + l16)*LDW + c*32 + quad*8);
            acc0 = __builtin_amdgcn_mfma_f32_16x16x32_bf16(a, b0v, acc0, 0, 0, 0);
            short8 b1v = *(const short8*)(Bs + (1*16 + l16)*LDW + c*32 + quad*8);
            acc1 = __builtin_amdgcn_mfma_f32_16x16x32_bf16(a, b1v, acc1, 0, 0, 0);
            short8 b2v = *(const short8*)(Bs + (2*16 + l16)*LDW + c*32 + quad*8);
            acc2 = __builtin_amdgcn_mfma_f32_16x16x32_bf16(a, b2v, acc2, 0, 0, 0);
            short8 b3v = *(const short8*)(Bs + (3*16 + l16)*LDW + c*32 + quad*8);
            acc3 = __builtin_amdgcn_mfma_f32_16x16x32_bf16(a, b3v, acc3, 0, 0, 0);
        }
    }

    if (VT_LAST && z == 2) {
        // write V-head transpose directly: vT[(bh*HDIM + hd)*SS + s]
        __syncthreads();   // all waves done reading As/Bs
        #pragma unroll
        for (int f = 0; f < 4; ++f) {
            f32x4 a = (f==0) ? acc0 : (f==1) ? acc1 : (f==2) ? acc2 : acc3;
            int col = f*16 + l16;           // hd within head
            float bv = HAS_BIAS ? bias[col0 + col] : 0.f;
            #pragma unroll
            for (int rg = 0; rg < 4; ++rg) {
                int rowl = w*16 + quad*4 + rg;   // s within tile
                As[col*72 + rowl] = f2bf(a[rg] + bv);   // As reused as [hd][s] (72-stride)
            }
        }
        __syncthreads();
        const int b_ = row0 >> 11;
        const int s0 = row0 & (SS - 1);
        const int h  = col0 >> 6;
        u16* dst = (u16*)Cp + ((size_t)((b_*NH + h)*HDIM + r))*SS + s0 + seg*16;
        ((uint4*)dst)[0] = *(const uint4*)(As + r*72 + seg*16);
        ((uint4*)dst)[1] = *(const uint4*)(As + r*72 + seg*16 + 8);
        return;
    }

    const float osc = (QSC && z == 0) ? 0.125f : 1.f;
    #pragma unroll
    for (int f = 0; f < 4; ++f) {
        f32x4 a = (f==0) ? acc0 : (f==1) ? acc1 : (f==2) ? acc2 : acc3;
        int col = col0 + f*16 + l16;
        float bv = HAS_BIAS ? bias[col] : 0.f;
        #pragma unroll
        for (int rg = 0; rg < 4; ++rg) {
            int rowg = row0 + w*16 + quad*4 + rg;
            float val = (a[rg] + bv) * osc;
            if (col >= nrowsB) val = 0.f;
            if (OUT_F32) ((float*)Cp)[(size_t)rowg*ldc + col] = val;
            else         ((u16*)Cp)[(size_t)rowg*ldc + col]  = f2bf(val);
        }
    }
}

// ---------------- fused attention, QBLK=128, 8 waves (no-max softmax) ----------------
#define QKT_8(BUF,sa0,sa1,sa2,sa3) do { \
    short8 b0 = *(const short8*)(BUF + (0*16 + l16)*72 + quad*8); \
    sa0 = __builtin_amdgcn_mfma_f32_16x16x32_bf16(q0, b0, sa0, 0,0,0); \
    short8 b0b = *(const short8*)(BUF + (0*16 + l16)*72 + 32 + quad*8); \
    sa0 = __builtin_amdgcn_mfma_f32_16x16x32_bf16(q1, b0b, sa0, 0,0,0); \
    short8 b1 = *(const short8*)(BUF + (1*16 + l16)*72 + quad*8); \
    sa1 = __builtin_amdgcn_mfma_f32_16x16x32_bf16(q0, b1, sa1, 0,0,0); \
    short8 b1b = *(const short8*)(BUF + (1*16 + l16)*72 + 32 + quad*8); \
    sa1 = __builtin_amdgcn_mfma_f32_16x16x32_bf16(q1, b1b, sa1, 0,0,0); \
    short8 b2 = *(const short8*)(BUF + (2*16 + l16)*72 + quad*8); \
    sa2 = __builtin_amdgcn_mfma_f32_16x16x32_bf16(q0, b2, sa2, 0,0,0); \
    short8 b2b = *(const short8*)(BUF + (2*16 + l16)*72 + 32 + quad*8); \
    sa2 = __builtin_amdgcn_mfma_f32_16x16x32_bf16(q1, b2b, sa2, 0,0,0); \
    short8 b3 = *(const short8*)(BUF + (3*16 + l16)*72 + quad*8); \
    sa3 = __builtin_amdgcn_mfma_f32_16x16x32_bf16(q0, b3, sa3, 0,0,0); \
    short8 b3b = *(const short8*)(BUF + (3*16 + l16)*72 + 32 + quad*8); \
    sa3 = __builtin_amdgcn_mfma_f32_16x16x32_bf16(q1, b3b, sa3, 0,0,0); \
} while (0)

// phase-1 sum update, interior tile (no masking)
static __device__ __forceinline__ void p1_int(
    const f32x4& sa0, const f32x4& sa1, const f32x4& sa2, const f32x4& sa3, float* l)
{
    #pragma unroll
    for (int rg = 0; rg < 4; ++rg) {
        l[rg] += (exp2_hw(sa0[rg]*LOG2E) + exp2_hw(sa1[rg]*LOG2E))
               + (exp2_hw(sa2[rg]*LOG2E) + exp2_hw(sa3[rg]*LOG2E));
    }
}
// phase-1 sum update, boundary tile (causal masking; all-true for waves above the diag)
static __device__ __forceinline__ void p1_diag(
    const f32x4& sa0, const f32x4& sa1, const f32x4& sa2, const f32x4& sa3,
    float* l, int key0, int qg0)
{
    #pragma unroll
    for (int rg = 0; rg < 4; ++rg) {
        int qg = qg0 + rg;
        float e0 = (key0      <= qg) ? exp2_hw(sa0[rg]*LOG2E) : 0.f;
        float e1 = (key0 + 16 <= qg) ? exp2_hw(sa1[rg]*LOG2E) : 0.f;
        float e2 = (key0 + 32 <= qg) ? exp2_hw(sa2[rg]*LOG2E) : 0.f;
        float e3 = (key0 + 48 <= qg) ? exp2_hw(sa3[rg]*LOG2E) : 0.f;
        l[rg] += (e0+e1) + (e2+e3);
    }
}

__global__ __launch_bounds__(512)
void attn_k(const u16* __restrict__ qh, const u16* __restrict__ kh,
            const u16* __restrict__ vT,
            float* __restrict__ attn_out, u16* __restrict__ Ob)
{
    __shared__ __align__(16) u16 Ks[64*72];
    __shared__ __align__(16) u16 Vs[64*72];
    __shared__ __align__(16) u16 Ps[128*72];
    const int blk = blockIdx.x;          // bh*16 + i
    const int i_ = blk & 15, bh = blk >> 4;
    const int b_ = bh >> 4, h = bh & (NH - 1);
    const int qbase = i_ * 128;
    const int qtTop = 2*i_ + 1;          // last k-tile index (odd)
    const int t = threadIdx.x, w = t >> 6, lane = t & 63, quad = lane >> 4, l16 = lane & 15;
    const int rs = t >> 3, seg8 = t & 7;     // K/V staging: 8 threads/row, 1 uint4 each
    const int r2 = t >> 2, seg = t & 3;      // zero-fill: 4 threads/row over 128 rows

    // q is pre-scaled by 1/8 at the projection epilogue (exact power-of-2)
    const u16* qrow = qh + (size_t)(b_*SS + qbase + w*16 + l16)*DD + h*HDIM;
    short8 q0 = *(const short8*)(qrow + quad*8);
    short8 q1 = *(const short8*)(qrow + 32 + quad*8);

    const u16* kstage = kh + (size_t)(b_*SS + rs)*DD + h*HDIM + seg8*8;
    const u16* vstage = vT + ((size_t)(bh*HDIM + rs))*SS + seg8*8;
    const int qg0 = qbase + w*16 + quad*4;

    // ---------------- phase 1: per-lane sum l, two K-tiles per barrier pair ----------------
    float l[4] = {0.f, 0.f, 0.f, 0.f};

    for (int kt0 = 0; kt0 <= qtTop; kt0 += 2) {   // qtTop odd -> always full pairs
        __syncthreads();
        {
            const u16* krow = kstage + (size_t)kt0*64*DD;
            *(uint4*)(Ks + rs*72 + seg8*8) = *(const uint4*)krow;
            *(uint4*)(Vs + rs*72 + seg8*8) = *(const uint4*)(krow + (size_t)64*DD);
        }
        __syncthreads();
        {
            f32x4 sa0 = 0.f, sa1 = 0.f, sa2 = 0.f, sa3 = 0.f;
            QKT_8(Ks, sa0, sa1, sa2, sa3);
            if (kt0 < 2*i_) p1_int(sa0, sa1, sa2, sa3, l);
            else            p1_diag(sa0, sa1, sa2, sa3, l, kt0*64 + l16, qg0);
        }
        {
            f32x4 sa0 = 0.f, sa1 = 0.f, sa2 = 0.f, sa3 = 0.f;
            QKT_8(Vs, sa0, sa1, sa2, sa3);
            if (kt0 < 2*i_) p1_int(sa0, sa1, sa2, sa3, l);
            else            p1_diag(sa0, sa1, sa2, sa3, l, (kt0+1)*64 + l16, qg0);
        }
    }

    // 16-lane sum merge; then fold 1/l into the exponent: lg2rl = -log2(l)
    float lg2rl[4];
    #pragma unroll
    for (int rg = 0; rg < 4; ++rg) {
        #pragma unroll
        for (int d = 1; d < 16; d <<= 1) l[rg] += __shfl_xor(l[rg], d);
        lg2rl[rg] = -__log2f(l[rg]);
    }

    // ---------------- phase 2: P write + O = P*V ----------------
    f32x4 oa0 = 0.f, oa1 = 0.f, oa2 = 0.f, oa3 = 0.f;
    float* attn_base = attn_out + (size_t)bh * SS * SS;
    float* rp0 = attn_base + (size_t)(qg0 + 0)*SS + l16;
    float* rp1 = attn_base + (size_t)(qg0 + 1)*SS + l16;
    float* rp2 = attn_base + (size_t)(qg0 + 2)*SS + l16;
    float* rp3 = attn_base + (size_t)(qg0 + 3)*SS + l16;
    const int psrow = w*16 + quad*4;

    for (int kt = 0; kt <= qtTop; ++kt) {
        __syncthreads();
        {
            const u16* krow = kstage + (size_t)kt*64*DD;
            *(uint4*)(Ks + rs*72 + seg8*8) = *(const uint4*)krow;
            const u16* vrow = vstage + kt*64;
            *(uint4*)(Vs + rs*72 + seg8*8) = *(const uint4*)vrow;
        }
        __syncthreads();

        f32x4 sa0 = 0.f, sa1 = 0.f, sa2 = 0.f, sa3 = 0.f;
        QKT_8(Ks, sa0, sa1, sa2, sa3);

        if (kt < 2*i_) {
            #pragma unroll
            for (int f = 0; f < 4; ++f) {
                f32x4 sv = (f==0) ? sa0 : (f==1) ? sa1 : (f==2) ? sa2 : sa3;
                float p0 = exp2_hw(__builtin_fmaf(sv[0], LOG2E, lg2rl[0]));
                float p1 = exp2_hw(__builtin_fmaf(sv[1], LOG2E, lg2rl[1]));
                float p2 = exp2_hw(__builtin_fmaf(sv[2], LOG2E, lg2rl[2]));
                float p3 = exp2_hw(__builtin_fmaf(sv[3], LOG2E, lg2rl[3]));
                rp0[f*16] = p0; rp1[f*16] = p1; rp2[f*16] = p2; rp3[f*16] = p3;
                u32 pk01 = cvtpk(p0, p1), pk23 = cvtpk(p2, p3);
                Ps[(psrow+0)*72 + f*16 + l16] = (u16)pk01;
                Ps[(psrow+1)*72 + f*16 + l16] = (u16)(pk01 >> 16);
                Ps[(psrow+2)*72 + f*16 + l16] = (u16)pk23;
                Ps[(psrow+3)*72 + f*16 + l16] = (u16)(pk23 >> 16);
            }
        } else {
            int kbase = kt*64;
            #pragma unroll
            for (int f = 0; f < 4; ++f) {
                f32x4 sv = (f==0) ? sa0 : (f==1) ? sa1 : (f==2) ? sa2 : sa3;
                int key = kbase + f*16 + l16;
                float p0 = (key <= qg0+0) ? exp2_hw(__builtin_fmaf(sv[0], LOG2E, lg2rl[0])) : 0.f;
                float p1 = (key <= qg0+1) ? exp2_hw(__builtin_fmaf(sv[1], LOG2E, lg2rl[1])) : 0.f;
                float p2 = (key <= qg0+2) ? exp2_hw(__builtin_fmaf(sv[2], LOG2E, lg2rl[2])) : 0.f;
                float p3 = (key <= qg0+3) ? exp2_hw(__builtin_fmaf(sv[3], LOG2E, lg2rl[3])) : 0.f;
                rp0[f*16] = p0; rp1[f*16] = p1; rp2[f*16] = p2; rp3[f*16] = p3;
                u32 pk01 = cvtpk(p0, p1), pk23 = cvtpk(p2, p3);
                Ps[(psrow+0)*72 + f*16 + l16] = (u16)pk01;
                Ps[(psrow+1)*72 + f*16 + l16] = (u16)(pk01 >> 16);
                Ps[(psrow+2)*72 + f*16 + l16] = (u16)pk23;
                Ps[(psrow+3)*72 + f*16 + l16] = (u16)(pk23 >> 16);
            }
        }
        rp0 += 64; rp1 += 64; rp2 += 64; rp3 += 64;

        // Ps rows are wave-private (wave w writes and reads rows w*16..w*16+15);
        // per-wave LDS pipe is in-order — compiler-level fence only, no barrier.
        asm volatile("" ::: "memory");

        // O += P * V
        #pragma unroll
        for (int c = 0; c < 2; ++c) {
            short8 pa = *(const short8*)(Ps + (w*16 + l16)*72 + c*32 + quad*8);
            short8 v0 = *(const short8*)(Vs + (0*16 + l16)*72 + c*32 + quad*8);
            oa0 = __builtin_amdgcn_mfma_f32_16x16x32_bf16(pa, v0, oa0, 0,0,0);
            short8 v1 = *(const short8*)(Vs + (1*16 + l16)*72 + c*32 + quad*8);
            oa1 = __builtin_amdgcn_mfma_f32_16x16x32_bf16(pa, v1, oa1, 0,0,0);
            short8 v2 = *(const short8*)(Vs + (2*16 + l16)*72 + c*32 + quad*8);
            oa2 = __builtin_amdgcn_mfma_f32_16x16x32_bf16(pa, v2, oa2, 0,0,0);
            short8 v3 = *(const short8*)(Vs + (3*16 + l16)*72 + c*32 + quad*8);
            oa3 = __builtin_amdgcn_mfma_f32_16x16x32_bf16(pa, v3, oa3, 0,0,0);
        }
    }

    // fully-masked upper tiles: explicit zeros (d_out is poisoned)
    for (int kt = qtTop + 1; kt < 32; ++kt) {
        int kbase = kt * 64;
        f32x4 z = 0.f;
        f32x4* p = (f32x4*)(attn_base + (size_t)(qbase + r2)*SS + kbase + seg*16);
        p[0] = z; p[1] = z; p[2] = z; p[3] = z;
    }

    #pragma unroll
    for (int f = 0; f < 4; ++f) {
        f32x4 ov = (f==0) ? oa0 : (f==1) ? oa1 : (f==2) ? oa2 : oa3;
        #pragma unroll
        for (int rg = 0; rg < 4; ++rg) {
            int qg = qg0 + rg;
            Ob[(size_t)(b_*SS + qg)*DD + h*HDIM + f*16 + l16] = f2bf(ov[rg]);
        }
    }
}

// ---------------- launch ----------------
extern "C" void kernel_launch(void* const* d_in, const int* in_sizes, int n_in,
                              void* d_out, int out_size, void* d_ws, size_t ws_size,
                              hipStream_t stream)
{
    const float* xs[3] = { (const float*)d_in[0], (const float*)d_in[1], (const float*)d_in[2] };
    const float* Vw[4] = { (const float*)d_in[3], (const float*)d_in[6], (const float*)d_in[9],  (const float*)d_in[12] };
    const float* Uw[4] = { (const float*)d_in[4], (const float*)d_in[7], (const float*)d_in[10], (const float*)d_in[13] };
    const float* bw[4] = { (const float*)d_in[5], (const float*)d_in[8], (const float*)d_in[11], (const float*)d_in[14] };

    char* ws = (char*)d_ws;
    size_t off = 0;
    auto alloc = [&](size_t bytes) -> char* {
        char* p = ws + off;
        off += (bytes + 255) & ~(size_t)255;
        return p;
    };
    u16* wV[4]; for (int i = 0; i < 4; ++i) wV[i] = (u16*)alloc((size_t)RK*DD*2);
    u16* wU[4]; for (int i = 0; i < 4; ++i) wU[i] = (u16*)alloc((size_t)DD*RKP*2);
    u16* Tb[3]; for (int i = 0; i < 3; ++i) Tb[i] = (u16*)alloc((size_t)BB*SS*RKP*2);
    u16* hb[2]; for (int i = 0; i < 2; ++i) hb[i] = (u16*)alloc((size_t)BB*SS*DD*2);
    u16* vTb = (u16*)alloc((size_t)BB*SS*DD*2);
    u16* Ob  = (u16*)alloc((size_t)BB*SS*DD*2);
    (void)ws_size; (void)in_sizes; (void)n_in; (void)out_size;

    // weight conversions: single launch, y 0..3 = V bf16, y 4..7 = U pad
    {
        C8 c = { { Vw[0], Vw[1], Vw[2], Vw[3], Uw[0], Uw[1], Uw[2], Uw[3] },
                 { wV[0], wV[1], wV[2], wV[3], wU[0], wU[1], wU[2], wU[3] } };
        cvt_all_k<<<dim3((DD*RKP + 255)/256, 8), 256, 0, stream>>>(c);
    }

    const int MROWS = BB*SS;           // 4096
    // stage 1 (q,k,v batched over z): X @ V^T -> T[4096x256 padded]
    {
        B3 g = { xs[0], xs[1], xs[2], wV[0], wV[1], wV[2],
                 nullptr, nullptr, nullptr, Tb[0], Tb[1], Tb[2] };
        gemm_nt_k<1,0,0,0,0><<<dim3(MROWS/64, RKP/64, 3), 256, 0, stream>>>(
            g, DD, DD, RK, RKP, DD);
    }
    // stage 2 (batched): T @ U^T + b -> qh (scaled 1/8), kh, vT (transposed epilogue)
    {
        B3 g = { Tb[0], Tb[1], Tb[2], wU[0], wU[1], wU[2],
                 bw[0], bw[1], bw[2], hb[0], hb[1], vTb };
        gemm_nt_k<0,0,1,1,1><<<dim3(MROWS/64, DD/64, 3), 256, 0, stream>>>(
            g, RKP, RKP, DD, DD, RKP);
    }

    float* attn_out = (float*)d_out + (size_t)BB*SS*DD;
    attn_k<<<BH*16, 512, 0, stream>>>(hb[0], hb[1], vTb, attn_out, Ob);

    // output projection: O @ Vo^T -> T; T @ Uo^T + bo -> d_out (fp32)
    {
        B3 g = { Ob, Ob, Ob, wV[3], wV[3], wV[3],
                 nullptr, nullptr, nullptr, Tb[0], Tb[0], Tb[0] };
        gemm_nt_k<0,0,0,0,0><<<dim3(MROWS/64, RKP/64, 1), 256, 0, stream>>>(
            g, DD, DD, RK, RKP, DD);
    }
    {
        B3 g = { Tb[0], Tb[0], Tb[0], wU[3], wU[3], wU[3],
                 bw[3], bw[3], bw[3], d_out, d_out, d_out };
        gemm_nt_k<0,1,1,0,0><<<dim3(MROWS/64, DD/64, 1), 256, 0, stream>>>(
            g, RKP, RKP, DD, DD, RKP);
    }
}